// Round 8
// baseline (147.754 us; speedup 1.0000x reference)
//
#include <hip/hip_runtime.h>

#define DIM 4096
using F2 = float2;
using F8 = __attribute__((ext_vector_type(8))) float;
using F2V = __attribute__((ext_vector_type(2))) float;

// R21 = R20 dataflow with TWO STATES PER BLOCK (ILP play).
// R20 accounting: v_pk_fma_f32 = 4 cyc/wave64 (2xf32/lane on SIMD-32), so
// essential pk work (~2.3k/wave) = ~9.2k cyc/wave; x8 waves/SIMD = 74k cyc
// ~= measured VALU busy (58% of 153k). Kernel is FMA-issue-bound at ~58%
// density; stalls are correlated (identical blocks hit the same transposes/
// barriers together, TLP can't fill). Fix: each block processes states 2b
// and 2b+1 (amp0/amp1, grid 1024, 4 blocks/CU): every stall has a second
// independent stream to issue from; barriers per state halve. LDS 32KB
// (state1 at psi+2048, f11 offset only -> identical banks/swizzles).
// Layouts/packings byte-identical R19/R20 (verified 5x). Coefs loaded once
// per gate (SMEM->SGPR), applied to both states.
// __launch_bounds__(256,1): min_waves>=6 proven to coerce the allocator
// into amp[] scratch spill (R16-R18); (.,1) never spilled (R13/R15/R19/R20).
//
// Address bits: qubit q <-> a[11-q]. Layouts (reg bit value in parens):
//  A : regs a11(8) a10(4) a9(2) a8(1); lanes a7..a2=l5..l0; wave a1a0
//      masks: q0:8 q1:4 q2:2 q3:1
//  B : regs a8(1) a7(4) a6(8) a5(2); lanes a11,a10,a9,a4,a3,a2=l5..l0; wave a1a0
//      masks: q3:1 q4:4 q5:8 q6:2
//  C : regs a5(2) a4(4) a3(8) a2(1); lanes a11..a6=l5..l0; wave a1a0
//      masks: q6:2 q7:4 q8:8 q9:1
//  D : regs a2(1) a1(2) a0(4) a11(8); lanes a10,a9,a8,a5,a4,a3=l5..l0; wave a7a6
//      masks: q9:1 q10:2 q11:4 q0:8
//  C': regs as C; lanes a11,a10,a9,a8,a1,a0=l5..l0; wave a7a6
//  B': = B.   A': = A.
// Transitions: T1 A->B del a8 SB=1 internal; T2 B->C del a5 SB=2 internal;
//  T3 C->D del a2 SB=1 CROSS; T4 D->C' del a2 SB=1 internal;
//  T5 C'->B' del a5 SB=2 CROSS; T6 B'->A' del a8 SB=1 internal.

// ---- scalar coefficient loads (SMEM) ----
__device__ __forceinline__ F8 sld8(const float* p) {
    F8 r;
    asm volatile("s_load_dwordx8 %0, %1, 0x0\n\ts_waitcnt lgkmcnt(0)"
                 : "=s"(r) : "s"(p));
    return r;
}
__device__ __forceinline__ void sld16(const float* pa, const float* pb, F8& a, F8& b) {
    asm volatile("s_load_dwordx8 %0, %2, 0x0\n\t"
                 "s_load_dwordx8 %1, %3, 0x0\n\t"
                 "s_waitcnt lgkmcnt(0)"
                 : "=&s"(a), "=&s"(b) : "s"(pa), "s"(pb));
}
__device__ __forceinline__ F2 sld2(const float* p) {
    F2V r;
    asm volatile("s_load_dwordx2 %0, %1, 0x0\n\ts_waitcnt lgkmcnt(0)"
                 : "=s"(r) : "s"(p));
    return F2{r[0], r[1]};
}

// ---- packed fp32 complex primitives (VOP3P), coefficient operand in SGPRs ----
__device__ __forceinline__ F2 pk_mul_bl(F2 a, F2 u) {   // (a.x*u.x, a.y*u.x)
    F2 d;
    asm("v_pk_mul_f32 %0, %1, %2 op_sel:[0,0] op_sel_hi:[1,0]"
        : "=v"(d) : "v"(a), "s"(u));
    return d;
}
__device__ __forceinline__ void pk_cross(F2& d, F2 a, F2 u) {  // d += (-a.y*u.y, a.x*u.y)
    asm("v_pk_fma_f32 %0, %1, %2, %0 op_sel:[1,1,0] op_sel_hi:[0,1,1] neg_lo:[1,0,0]"
        : "+v"(d) : "v"(a), "s"(u));
}
__device__ __forceinline__ void pk_fma_bl(F2& d, F2 a, F2 u) { // d += (a.x*u.x, a.y*u.x)
    asm("v_pk_fma_f32 %0, %1, %2, %0 op_sel:[0,0,0] op_sel_hi:[1,0,1]"
        : "+v"(d) : "v"(a), "s"(u));
}
__device__ __forceinline__ void pk_swapneg(F2& d, F2 a, F2 cs) { // d += (a.y*cs.y, -a.x*cs.y)
    asm("v_pk_fma_f32 %0, %1, %2, %0 op_sel:[1,1,0] op_sel_hi:[0,1,1] neg_hi:[1,0,0]"
        : "+v"(d) : "v"(a), "s"(cs));
}
// all-VGPR variants (expv: both operands are lane data)
__device__ __forceinline__ void pk_fma(F2& d, F2 a, F2 b) {    // d += a*b
    asm("v_pk_fma_f32 %0, %1, %2, %0" : "+v"(d) : "v"(a), "v"(b));
}
__device__ __forceinline__ void pk_imacc(F2& d, F2 a0, F2 a1) { // d += (a0.x*a1.y, -a0.y*a1.x)
    asm("v_pk_fma_f32 %0, %1, %2, %0 op_sel:[0,1,0] op_sel_hi:[1,0,1] neg_hi:[1,0,0]"
        : "+v"(d) : "v"(a0), "v"(a1));
}
__device__ __forceinline__ F2 pk_cmul(F2 u, F2 a) {
    F2 d = pk_mul_bl(a, u);
    pk_cross(d, a, u);
    return d;
}
__device__ __forceinline__ void pk_cfma(F2& d, F2 u, F2 a) {
    pk_fma_bl(d, a, u);
    pk_cross(d, a, u);
}

__device__ __forceinline__ void build_u(float tx, float ty, float tz, float* u) {
    float sx = sinf(0.5f*tx), cx = cosf(0.5f*tx);
    float sy = sinf(0.5f*ty), cy = cosf(0.5f*ty);
    float sz = sinf(0.5f*tz), cz = cosf(0.5f*tz);
    float A00r = cy*cx, A00i =  sy*sx;     // A = Ry*Rx
    float A01r = -sy*cx, A01i = -cy*sx;
    float A10r =  sy*cx, A10i = -cy*sx;
    float A11r =  cy*cx, A11i = -sy*sx;
    // U = Rz*A: row0 *= (cz - i sz), row1 *= (cz + i sz)   [verified r1/3/5..20]
    u[0] = cz*A00r + sz*A00i;  u[1] = cz*A00i - sz*A00r;
    u[2] = cz*A01r + sz*A01i;  u[3] = cz*A01i - sz*A01r;
    u[4] = cz*A10r - sz*A10i;  u[5] = cz*A10i + sz*A10r;
    u[6] = cz*A11r - sz*A11i;  u[7] = cz*A11i + sz*A11r;
}

// coef layout (floats): [0..95] U0 plain (q*8); [96..191] RX(ang[36+q-1])*U0[q] (q=1..11);
// [192..287] U1 plain; [288..295] U1[0]*RX(ang[47]); [296..319] L1 CRX (cos,sin)[c=0..11]
__global__ void prep_kernel(const float* __restrict__ ang, float* __restrict__ coef) {
    int t = threadIdx.x;
    if (t < 12) {
        float u[8]; build_u(ang[t], ang[12+t], ang[24+t], u);
#pragma unroll
        for (int j = 0; j < 8; ++j) coef[t*8 + j] = u[j];
    } else if (t < 24) {
        int q = t - 12;
        float u[8]; build_u(ang[48+q], ang[60+q], ang[72+q], u);
#pragma unroll
        for (int j = 0; j < 8; ++j) coef[192 + q*8 + j] = u[j];
    } else if (t < 36) {
        int c = t - 24;
        float th = 0.5f * ang[95 - c];     // L1 ring gate (c,c+1) = tape slot 84+(11-c)
        coef[296 + c*2]     = cosf(th);
        coef[296 + c*2 + 1] = sinf(th);
    } else if (t < 47) {
        int q = t - 35;                    // 1..11: M = RX(ang[36+q-1]) * U0[q]
        float u[8]; build_u(ang[q], ang[12+q], ang[24+q], u);
        float c = cosf(0.5f*ang[36+q-1]), s = sinf(0.5f*ang[36+q-1]);
        float m[8];
        m[0] = c*u[0] + s*u[5];  m[1] = c*u[1] - s*u[4];   // M00 = c u00 - i s u10
        m[2] = c*u[2] + s*u[7];  m[3] = c*u[3] - s*u[6];   // M01 = c u01 - i s u11
        m[4] = s*u[1] + c*u[4];  m[5] = -s*u[0] + c*u[5];  // M10 = -i s u00 + c u10
        m[6] = s*u[3] + c*u[6];  m[7] = -s*u[2] + c*u[7];  // M11 = -i s u01 + c u11
#pragma unroll
        for (int j = 0; j < 8; ++j) coef[96 + q*8 + j] = m[j];
    } else if (t == 47) {                  // M = U1[0] * RX(ang[47])  [CR0(11,0) then U1(0)]
        float u[8]; build_u(ang[48], ang[60], ang[72], u);
        float c = cosf(0.5f*ang[47]), s = sinf(0.5f*ang[47]);
        float m[8];
        m[0] = c*u[0] + s*u[3];  m[1] = c*u[1] - s*u[2];   // M00 = c u00 - i s u01
        m[2] = s*u[1] + c*u[2];  m[3] = -s*u[0] + c*u[3];  // M01 = -i s u00 + c u01
        m[4] = c*u[4] + s*u[7];  m[5] = c*u[5] - s*u[6];   // M10 = c u10 - i s u11
        m[6] = s*u[5] + c*u[6];  m[7] = -s*u[4] + c*u[7];  // M11 = -i s u10 + c u11
#pragma unroll
        for (int j = 0; j < 8; ++j) coef[288 + j] = m[j];
    }
}

// ---- register-part (compile-time per unrolled r) of each packing ----
__device__ __forceinline__ int rpA1(int r) {   // T1/T6, A side (a8 deleted = r&1)
    int a11=(r>>3)&1, a10=(r>>2)&1, a9=(r>>1)&1;
    return (a11<<8)|(a10<<7)|(a9<<6)|(a11<<3)|(a10<<2)|(a9<<1)|(a9<<0);
}
__device__ __forceinline__ int rpB1(int r) {   // T1/T6, B side
    int a5=(r>>1)&1, a7=(r>>2)&1, a6=(r>>3)&1;
    return (a7<<5)|(a6<<4)|(a7<<3)|(a6<<2)|(a5<<0);
}
__device__ __forceinline__ int rpB2(int r) {   // T2, B side (a5 deleted = r&2)
    int a8=r&1, a7=(r>>2)&1, a6=(r>>3)&1;
    return (a8<<5)|(a7<<4)|(a6<<3)|(a7<<2)|(a8<<1)|(a6<<0);
}
__device__ __forceinline__ int rpC2(int r) {   // T2, C side
    int a2=r&1, a4=(r>>2)&1, a3=(r>>3)&1;
    return (a3<<3)|(a2<<2)|(a4<<1);
}
__device__ __forceinline__ int rpC3(int r) {   // T3/T4, C/C' side (a2 deleted = r&1)
    int a5=(r>>1)&1, a4=(r>>2)&1, a3=(r>>3)&1;
    return (a5<<4)|(a3<<3)|(a4<<2)|(a5<<0);
}
__device__ __forceinline__ int rpD3(int r) {   // T3/T4, D side
    int a1=(r>>1)&1, a0=(r>>2)&1, a11=(r>>3)&1;
    return (a11<<8)|(a11<<3)|(a1<<1)|((a0^a11)<<0);
}
__device__ __forceinline__ int rpC5(int r) {   // T5, C' side (a5 deleted = r&2)
    int a2=r&1, a4=(r>>2)&1, a3=(r>>3)&1;
    return (a4<<4)|(a3<<3)|(a2<<2)|(a4<<0);
}
__device__ __forceinline__ int rpB5(int r) {   // T5, B' side
    int a8=r&1, a7=(r>>2)&1, a6=(r>>3)&1;
    return (a7<<10)|(a6<<9)|(a8<<5)|(a8<<3);
}

// ---- tile pointers (lane/wave part of each packing); scoped per transpose ----
#define LBITS \
    const int l0=l&1, l1=(l>>1)&1, l2=(l>>2)&1, l3=(l>>3)&1, l4=(l>>4)&1, \
              l5=(l>>5)&1, w0=w&1, w1=(w>>1)&1; \
    (void)l0;(void)l1;(void)l2;(void)l3;(void)l4;(void)l5;(void)w0;(void)w1;

__device__ __forceinline__ int tpA1f(int l, int w) { LBITS
    return (w1<<10)|(w0<<9)|(l5<<5)|(l4<<4)|((l1^l5)<<3)|((l0^l4)<<2)|(l2<<1)|(l3<<0); }
__device__ __forceinline__ int tpB1f(int l, int w) { LBITS
    return (w1<<10)|(w0<<9)|(l5<<8)|(l4<<7)|(l3<<6)|((l1^l5)<<3)|((l0^l4)<<2)|((l2^l3)<<1)|(l3<<0); }
__device__ __forceinline__ int tpC2f(int l, int w) { LBITS
    return (w1<<10)|(w0<<9)|(l5<<8)|(l4<<7)|(l3<<6)|(l2<<5)|(l1<<4)|((l5^l0)<<3)|((l4^l1)<<2)|((l3^l2)<<1)|((l0^l3)<<0); }
__device__ __forceinline__ int tpC3f(int l, int w) { LBITS
    return (l1<<10)|(l0<<9)|(l5<<8)|(l4<<7)|(l3<<6)|(l2<<5)|((l5^l4)<<3)|(l3<<2)|((w1^l2)<<1)|((w0^l5)<<0); }
__device__ __forceinline__ int tpD3f(int l, int w) { LBITS
    return (w1<<10)|(w0<<9)|(l5<<7)|(l4<<6)|(l3<<5)|(l2<<4)|((l0^l5)<<3)|((l1^l4)<<2)|(l3<<1)|(l2<<0); }
__device__ __forceinline__ int tpC4f(int l, int w) { LBITS
    return (w1<<10)|(w0<<9)|(l5<<8)|(l4<<7)|(l3<<6)|(l2<<5)|((l5^l4)<<3)|(l3<<2)|((l1^l2)<<1)|((l0^l5)<<0); }
__device__ __forceinline__ int tpC5f(int l, int w) { LBITS
    return (w1<<10)|(w0<<9)|(l5<<8)|(l4<<7)|(l3<<6)|(l2<<5)|((l5^l2)<<3)|(l4<<2)|((l1^l3)<<1)|(l0<<0); }
__device__ __forceinline__ int tpB5f(int l, int w) { LBITS
    return (l5<<8)|(l4<<7)|(l3<<6)|(l2<<4)|((l1^l5)<<3)|((l0^l4)<<2)|((w1^l3)<<1)|((w0^l2)<<0); }

// Plain 1q gate over subset {r0: (r0&M)==0, (S1==0 || (r0&S1)==H1)};
// coefficients in SGPRs.
template<int M, int S1, int H1>
__device__ __forceinline__ void g1q(F2* amp, F2 u00, F2 u01, F2 u10, F2 u11) {
#pragma unroll
    for (int r0 = 0; r0 < 16; ++r0) {
        if (r0 & M) continue;
        if (S1 != 0 && (r0 & S1) != H1) continue;
        const int r1 = r0 + M;
        F2 a0 = amp[r0], a1 = amp[r1];
        F2 n0 = pk_cmul(u00, a0); pk_cfma(n0, u01, a1);
        F2 n1 = pk_cmul(u10, a0); pk_cfma(n1, u11, a1);
        amp[r0] = n0; amp[r1] = n1;
    }
}
template<int M, int S1, int H1>
__device__ __forceinline__ void g1qF(F2* amp, F8 u) {
    g1q<M, S1, H1>(amp, F2{u[0],u[1]}, F2{u[2],u[3]}, F2{u[4],u[5]}, F2{u[6],u[7]});
}

// Fused gate: matrix selected per pair by compile-time control bit MSEL.
template<int MSEL, int M, int S1, int H1>
__device__ __forceinline__ void fg1q(F2* amp, F2 a00, F2 a01, F2 a10, F2 a11,
                                     F2 b00, F2 b01, F2 b10, F2 b11) {
#pragma unroll
    for (int r0 = 0; r0 < 16; ++r0) {
        if (r0 & M) continue;
        if (S1 != 0 && (r0 & S1) != H1) continue;
        const int r1 = r0 + M;
        const bool sel = (r0 & MSEL) != 0;           // compile-time
        F2 u00 = sel ? b00 : a00, u01 = sel ? b01 : a01;
        F2 u10 = sel ? b10 : a10, u11 = sel ? b11 : a11;
        F2 a0 = amp[r0], a1 = amp[r1];
        F2 n0 = pk_cmul(u00, a0); pk_cfma(n0, u01, a1);
        F2 n1 = pk_cmul(u10, a0); pk_cfma(n1, u11, a1);
        amp[r0] = n0; amp[r1] = n1;
    }
}
template<int MSEL, int M, int S1, int H1>
__device__ __forceinline__ void fg1qF(F2* amp, F8 a, F8 b) {
    fg1q<MSEL, M, S1, H1>(amp,
        F2{a[0],a[1]}, F2{a[2],a[3]}, F2{a[4],a[5]}, F2{a[6],a[7]},
        F2{b[0],b[1]}, F2{b[2],b[3]}, F2{b[4],b[5]}, F2{b[6],b[7]});
}

template<int MC, int MT>
__device__ __forceinline__ void crx(F2* amp, F2 cs) {   // cs in SGPRs
#pragma unroll
    for (int r0 = 0; r0 < 16; ++r0) {
        if (!(r0 & MC) || (r0 & MT)) continue;
        const int r1 = r0 + MT;
        F2 a0 = amp[r0], a1 = amp[r1];
        F2 n0 = pk_mul_bl(a0, cs); pk_swapneg(n0, a1, cs);
        F2 n1 = pk_mul_bl(a1, cs); pk_swapneg(n1, a0, cs);
        amp[r0] = n0; amp[r1] = n1;
    }
}

template<int M>
__device__ __forceinline__ void expv(const F2* amp, int q, int lane,
                                     float& fx, float& fy, float& fz) {
    F2 zp = {0.f, 0.f}, zm = {0.f, 0.f}, xp = {0.f, 0.f}, ip = {0.f, 0.f};
#pragma unroll
    for (int r0 = 0; r0 < 16; ++r0) {
        if (r0 & M) continue;
        const int r1 = r0 + M;
        F2 a0 = amp[r0], a1 = amp[r1];
        pk_fma(zp, a0, a0);
        pk_fma(zm, a1, a1);
        pk_fma(xp, a0, a1);
        pk_imacc(ip, a0, a1);
    }
    float zz = (zp.x + zp.y) - (zm.x + zm.y);
    float xr = 2.f * (xp.x + xp.y);
    float xi = 2.f * (ip.x + ip.y);
#pragma unroll
    for (int off = 32; off; off >>= 1) {
        xr += __shfl_xor(xr, off);
        xi += __shfl_xor(xi, off);
        zz += __shfl_xor(zz, off);
    }
    if (lane == q) { fx = xr; fy = xi; fz = zz; }
}

// enumerate j-th pair base r0 with (r0 & M)==0 and (r0 & SB)==hb*SB (4-bit regs)
template<int M, int SB>
__device__ __forceinline__ int r0_of(int j, int hb) {
    int r = hb ? SB : 0, b = 1;
#pragma unroll
    for (int p = 0; p < 4; ++p) {
        const int mm = 1 << p;
        if (mm == M || mm == SB) continue;
        if (j & b) r |= mm;
        b <<= 1;
    }
    return r;
}

// Store one half (8 regs with (r & SB) == HB) of state in buffer PS.
#define ST_T(AMP, PS, TP, RP, SB, HB) \
  { _Pragma("unroll") for (int r = 0; r < 16; ++r) { \
      if ((r & (SB)) != (HB)) continue; \
      (PS)[(TP) ^ RP(r)] = AMP[r]; } }
// Load one half in pair order of the next gate (mask M).
#define LD_T(AMP, PS, TP, RP, M, SB, HB) \
  { _Pragma("unroll") for (int k = 0; k < 8; ++k) { \
      const int j = k >> 1; \
      const int r0 = r0_of<M, SB>(j, (HB) != 0); \
      const int r = (k & 1) ? (r0 + (M)) : r0; \
      AMP[r] = (PS)[(TP) ^ RP(r)]; } }

// gate macros: load coefficients ONCE (SMEM->SGPR), apply to both states
#define U0P(q, M)    do { F8 u_ = sld8(cf + (q)*8); \
                          g1qF<M, 0, 0>(amp0, u_); g1qF<M, 0, 0>(amp1, u_); } while(0)
#define FU0(q, MS, M) do { F8 ua_, ub_; sld16(cf + (q)*8, cf + 96 + (q)*8, ua_, ub_); \
                           fg1qF<MS, M, 0, 0>(amp0, ua_, ub_); \
                           fg1qF<MS, M, 0, 0>(amp1, ua_, ub_); } while(0)
#define U1P(q, M)    do { F8 u_ = sld8(cf + 192 + (q)*8); \
                          g1qF<M, 0, 0>(amp0, u_); g1qF<M, 0, 0>(amp1, u_); } while(0)
#define FU1_0()      do { F8 ua_, ub_; sld16(cf + 192, cf + 288, ua_, ub_); \
                          fg1qF<4, 8, 0, 0>(amp0, ua_, ub_); \
                          fg1qF<4, 8, 0, 0>(amp1, ua_, ub_); } while(0)
#define CR1(c, MC, MT) do { F2 cs_ = sld2(cf + 296 + (c)*2); \
                            crx<MC, MT>(amp0, cs_); crx<MC, MT>(amp1, cs_); } while(0)
#define EXPV(q, M)   do { expv<M>(amp0, q, l, fx0, fy0, fz0); \
                          expv<M>(amp1, q, l, fx1, fy1, fz1); } while(0)

__global__ __launch_bounds__(256, 1)
void qsim_kernel(const float* __restrict__ sv,      // [B, 4096]
                 const float* __restrict__ cf,      // [320] precomputed coefficients
                 const float* __restrict__ W,       // [10, 36]
                 const float* __restrict__ bvec,    // [10]
                 float* __restrict__ out)           // [B, 10]
{
    __shared__ F2 psi[4096];         // 32 KB: state0 [0..2047], state1 [2048..4095]
    F2* const psi1 = psi + 2048;
    const int t = threadIdx.x;
    const int b = blockIdx.x;
    const int l = t & 63, w = t >> 6;

    F2 amp0[16], amp1[16];
    const float* svb0 = sv + (size_t)(2 * b) * DIM;
    const float* svb1 = svb0 + DIM;
    // layout A: idx = r<<8 | l<<2 | w; pair order for U0P(0, M=8)
#pragma unroll
    for (int k = 0; k < 16; ++k) {
        const int r = (k & 1) ? ((k >> 1) + 8) : (k >> 1);
        const int idx = (r << 8) | (l << 2) | w;
        amp0[r] = make_float2(svb0[idx], 0.f);
        amp1[r] = make_float2(svb1[idx], 0.f);
    }

    float fx0 = 0.f, fy0 = 0.f, fz0 = 0.f;
    float fx1 = 0.f, fy1 = 0.f, fz1 = 0.f;

    // ---- A {q0:8 q1:4 q2:2 q3:1}: U0(0); [U0;CR0] q=1..3 ----
    U0P(0, 8);
    FU0(1, 8, 4); FU0(2, 4, 2); FU0(3, 2, 1);

    // ---- T1 A->B (internal, del a8, SB=1): halfgate FU0(4,1,4) ----
    {
        F8 ua, ub; sld16(cf + 4*8, cf + 96 + 4*8, ua, ub);
        const int tpA = tpA1f(l, w), tpB = tpB1f(l, w);
        ST_T(amp0, psi,  tpA, rpA1, 1, 0);
        ST_T(amp1, psi1, tpA, rpA1, 1, 0);
        LD_T(amp0, psi,  tpB, rpB1, 4, 1, 0);
        LD_T(amp1, psi1, tpB, rpB1, 4, 1, 0);
        ST_T(amp0, psi,  tpA, rpA1, 1, 1);
        ST_T(amp1, psi1, tpA, rpA1, 1, 1);
        fg1qF<1, 4, 1, 0>(amp0, ua, ub);
        fg1qF<1, 4, 1, 0>(amp1, ua, ub);
        LD_T(amp0, psi,  tpB, rpB1, 4, 1, 1);
        LD_T(amp1, psi1, tpB, rpB1, 4, 1, 1);
        fg1qF<1, 4, 1, 1>(amp0, ua, ub);
        fg1qF<1, 4, 1, 1>(amp1, ua, ub);
    }
    // ---- B {q3:1 q4:4 q5:8 q6:2} ----
    FU0(5, 4, 8); FU0(6, 8, 2);

    // ---- T2 B->C (internal, del a5, SB=2): halfgate FU0(7,2,4) ----
    {
        F8 ua, ub; sld16(cf + 7*8, cf + 96 + 7*8, ua, ub);
        const int tpB = tpB1f(l, w), tpC = tpC2f(l, w);
        ST_T(amp0, psi,  tpB, rpB2, 2, 0);
        ST_T(amp1, psi1, tpB, rpB2, 2, 0);
        LD_T(amp0, psi,  tpC, rpC2, 4, 2, 0);
        LD_T(amp1, psi1, tpC, rpC2, 4, 2, 0);
        ST_T(amp0, psi,  tpB, rpB2, 2, 2);
        ST_T(amp1, psi1, tpB, rpB2, 2, 2);
        fg1qF<2, 4, 2, 0>(amp0, ua, ub);
        fg1qF<2, 4, 2, 0>(amp1, ua, ub);
        LD_T(amp0, psi,  tpC, rpC2, 4, 2, 2);
        LD_T(amp1, psi1, tpC, rpC2, 4, 2, 2);
        fg1qF<2, 4, 2, 2>(amp0, ua, ub);
        fg1qF<2, 4, 2, 2>(amp1, ua, ub);
    }
    // ---- C {q6:2 q7:4 q8:8 q9:1} ----
    FU0(8, 4, 8); FU0(9, 8, 1);

    // ---- T3 C->D (CROSS, del a2, SB=1): halfgate FU0(10,1,2) ----
    {
        F8 ua, ub; sld16(cf + 10*8, cf + 96 + 10*8, ua, ub);
        __syncthreads();             // T2 slots not wave-disjoint vs T3 stores
        const int tpC = tpC3f(l, w), tpD = tpD3f(l, w);
        ST_T(amp0, psi,  tpC, rpC3, 1, 0);
        ST_T(amp1, psi1, tpC, rpC3, 1, 0);
        __syncthreads();
        LD_T(amp0, psi,  tpD, rpD3, 2, 1, 0);
        LD_T(amp1, psi1, tpD, rpD3, 2, 1, 0);
        __syncthreads();
        ST_T(amp0, psi,  tpC, rpC3, 1, 1);
        ST_T(amp1, psi1, tpC, rpC3, 1, 1);
        fg1qF<1, 2, 1, 0>(amp0, ua, ub);
        fg1qF<1, 2, 1, 0>(amp1, ua, ub);
        __syncthreads();
        LD_T(amp0, psi,  tpD, rpD3, 2, 1, 1);
        LD_T(amp1, psi1, tpD, rpD3, 2, 1, 1);
        fg1qF<1, 2, 1, 1>(amp0, ua, ub);
        fg1qF<1, 2, 1, 1>(amp1, ua, ub);
    }
    // ---- D {q9:1 q10:2 q11:4 q0:8}: [CR0(11,0);U1(0)]; U1(9..11);
    //      L1 ring (11,0),(10,11),(9,10); expv 10,11 ----
    FU0(11, 2, 4);
    FU1_0();
    U1P(9, 1); U1P(10, 2); U1P(11, 4);
    CR1(11, 4, 8); CR1(10, 2, 4); CR1(9, 1, 2);
    EXPV(10, 2); EXPV(11, 4);

    // ---- T4 D->C' (internal, del a2, SB=1): halfgate U1P(7,4) ----
    // no barrier: T3-LD and T4-ST slots both carry a7a6=wave at f10,f9
    {
        F8 u7 = sld8(cf + 192 + 7*8);
        const int tpD = tpD3f(l, w), tpC = tpC4f(l, w);
        ST_T(amp0, psi,  tpD, rpD3, 1, 0);
        ST_T(amp1, psi1, tpD, rpD3, 1, 0);
        LD_T(amp0, psi,  tpC, rpC3, 4, 1, 0);
        LD_T(amp1, psi1, tpC, rpC3, 4, 1, 0);
        ST_T(amp0, psi,  tpD, rpD3, 1, 1);
        ST_T(amp1, psi1, tpD, rpD3, 1, 1);
        g1qF<4, 1, 0>(amp0, u7);
        g1qF<4, 1, 0>(amp1, u7);
        LD_T(amp0, psi,  tpC, rpC3, 4, 1, 1);
        LD_T(amp1, psi1, tpC, rpC3, 4, 1, 1);
        g1qF<4, 1, 1>(amp0, u7);
        g1qF<4, 1, 1>(amp1, u7);
    }
    // ---- C' {q6:2 q7:4 q8:8 q9:1}: U1(6,8); ring (8,9),(7,8),(6,7); expv 7,8,9 ----
    U1P(6, 2); U1P(8, 8);
    CR1(8, 8, 1); CR1(7, 4, 8); CR1(6, 2, 4);
    EXPV(9, 1); EXPV(8, 8); EXPV(7, 4);

    // ---- T5 C'->B' (CROSS, del a5, SB=2): halfgate U1P(3,1) ----
    // no leading barrier: T4-LD and T5-ST slots both carry a7a6=wave at f10,f9
    {
        F8 u3 = sld8(cf + 192 + 3*8);
        const int tpC = tpC5f(l, w), tpB = tpB5f(l, w);
        ST_T(amp0, psi,  tpC, rpC5, 2, 0);
        ST_T(amp1, psi1, tpC, rpC5, 2, 0);
        __syncthreads();
        LD_T(amp0, psi,  tpB, rpB5, 1, 2, 0);
        LD_T(amp1, psi1, tpB, rpB5, 1, 2, 0);
        __syncthreads();
        ST_T(amp0, psi,  tpC, rpC5, 2, 2);
        ST_T(amp1, psi1, tpC, rpC5, 2, 2);
        g1qF<1, 2, 0>(amp0, u3);
        g1qF<1, 2, 0>(amp1, u3);
        __syncthreads();
        LD_T(amp0, psi,  tpB, rpB5, 1, 2, 2);
        LD_T(amp1, psi1, tpB, rpB5, 1, 2, 2);
        g1qF<1, 2, 2>(amp0, u3);
        g1qF<1, 2, 2>(amp1, u3);
        __syncthreads();             // protect cross-wave reads from T6 stores
    }
    // ---- B' {q3:1 q4:4 q5:8 q6:2}: U1(4,5); ring (5,6),(4,5),(3,4); expv 4,5,6 ----
    U1P(4, 4); U1P(5, 8);
    CR1(5, 8, 2); CR1(4, 4, 8); CR1(3, 1, 4);
    EXPV(6, 2); EXPV(5, 8); EXPV(4, 4);

    // ---- T6 B'->A' (internal, del a8, SB=1): halfgate U1P(1,4) ----
    {
        F8 u1 = sld8(cf + 192 + 1*8);
        const int tpB = tpB1f(l, w), tpA = tpA1f(l, w);
        ST_T(amp0, psi,  tpB, rpB1, 1, 0);
        ST_T(amp1, psi1, tpB, rpB1, 1, 0);
        LD_T(amp0, psi,  tpA, rpA1, 4, 1, 0);
        LD_T(amp1, psi1, tpA, rpA1, 4, 1, 0);
        ST_T(amp0, psi,  tpB, rpB1, 1, 1);
        ST_T(amp1, psi1, tpB, rpB1, 1, 1);
        g1qF<4, 1, 0>(amp0, u1);
        g1qF<4, 1, 0>(amp1, u1);
        LD_T(amp0, psi,  tpA, rpA1, 4, 1, 1);
        LD_T(amp1, psi1, tpA, rpA1, 4, 1, 1);
        g1qF<4, 1, 1>(amp0, u1);
        g1qF<4, 1, 1>(amp1, u1);
    }
    // ---- A' {q0:8 q1:4 q2:2 q3:1}: U1(2); ring (2,3),(1,2),(0,1); expv 0..3 ----
    U1P(2, 2);
    CR1(2, 2, 1); CR1(1, 4, 2); CR1(0, 8, 4);
    EXPV(3, 1); EXPV(2, 2); EXPV(1, 4); EXPV(0, 8);

    // ---- combine 4 waves' partial features, 2 states ----
    __syncthreads();                 // psi dead only after all waves' T6 loads
    float* fbuf = (float*)psi;       // [2][4][36]
    if (l < 12) {
        float* f0 = fbuf + w * 36;
        f0[l] = fx0;  f0[12 + l] = fy0;  f0[24 + l] = fz0;
        float* f1 = fbuf + 144 + w * 36;
        f1[l] = fx1;  f1[12 + l] = fy1;  f1[24 + l] = fz1;
    }
    __syncthreads();
    if (t < 20) {
        const int s = t / 10, row = t % 10;
        const float* fb = fbuf + s * 144;
        float a = bvec[row];
#pragma unroll
        for (int f = 0; f < 36; ++f)
            a += W[row * 36 + f] * (fb[f] + fb[36 + f] + fb[72 + f] + fb[108 + f]);
        out[(size_t)(2 * b + s) * 10 + row] = a;
    }
}

extern "C" void kernel_launch(void* const* d_in, const int* in_sizes, int n_in,
                              void* d_out, int out_size, void* d_ws, size_t ws_size,
                              hipStream_t stream) {
    const float* sv     = (const float*)d_in[0];
    const float* angles = (const float*)d_in[1];
    const float* W      = (const float*)d_in[2];
    const float* bvec   = (const float*)d_in[3];
    float* out  = (float*)d_out;
    float* coef = (float*)d_ws;      // 320 floats of scratch
    int batch = in_sizes[0] / DIM;   // 2048
    prep_kernel<<<1, 64, 0, stream>>>(angles, coef);
    qsim_kernel<<<batch / 2, 256, 0, stream>>>(sv, coef, W, bvec, out);
}

// Round 9
// 127.514 us; speedup vs baseline: 1.1587x; 1.1587x over previous
//
#include <hip/hip_runtime.h>

#define DIM 4096
using F2 = float2;
using F8 = __attribute__((ext_vector_type(8))) float;
using F2V = __attribute__((ext_vector_type(2))) float;

// R22 = R20 (champion, qsim 64.0 us, VGPR 64, 8 waves/SIMD) + DPP wave-sum
// in expv. R21 post-mortem: 2-state ILP pushed VGPR to 124 -> 4 waves/SIMD
// -> 77 us; dead end. R20 accounting: VALU pk-floor ~67k cyc/SIMD (58%
// busy) AND LDS pipe ~100k cyc/CU occupied (6 transposes x 32 b64 ops +
// 12 expv x 18 ds_swizzle shuffles + init) -> LDS is co-bottleneck.
// Fix: expv reduction via VALU-only DPP chain (row_shr:1/2/4/8,
// row_bcast15, row_bcast31 -> total in lane 63, readlane broadcast):
// removes 216 ds_swizzle ops/wave from the LDS pipe, VALU-neutral.
// Everything else byte-identical to R20 (harness-verified 6x).
//
// Address bits: qubit q <-> a[11-q]. Layouts (reg bit value in parens):
//  A : regs a11(8) a10(4) a9(2) a8(1); lanes a7..a2=l5..l0; wave a1a0
//      masks: q0:8 q1:4 q2:2 q3:1
//  B : regs a8(1) a7(4) a6(8) a5(2); lanes a11,a10,a9,a4,a3,a2=l5..l0; wave a1a0
//      masks: q3:1 q4:4 q5:8 q6:2
//  C : regs a5(2) a4(4) a3(8) a2(1); lanes a11..a6=l5..l0; wave a1a0
//      masks: q6:2 q7:4 q8:8 q9:1
//  D : regs a2(1) a1(2) a0(4) a11(8); lanes a10,a9,a8,a5,a4,a3=l5..l0; wave a7a6
//      masks: q9:1 q10:2 q11:4 q0:8
//  C': regs as C; lanes a11,a10,a9,a8,a1,a0=l5..l0; wave a7a6
//  B': = B.   A': = A.
// Transitions: T1 A->B del a8 SB=1 internal; T2 B->C del a5 SB=2 internal;
//  T3 C->D del a2 SB=1 CROSS; T4 D->C' del a2 SB=1 internal;
//  T5 C'->B' del a5 SB=2 CROSS; T6 B'->A' del a8 SB=1 internal.
// __launch_bounds__(256,1): min_waves>=6 coerces allocator into amp[]
// scratch spill (R16-R18 forensics); (.,1) never spilled.

// ---- scalar coefficient loads (SMEM) ----
__device__ __forceinline__ F8 sld8(const float* p) {
    F8 r;
    asm volatile("s_load_dwordx8 %0, %1, 0x0\n\ts_waitcnt lgkmcnt(0)"
                 : "=s"(r) : "s"(p));
    return r;
}
__device__ __forceinline__ void sld16(const float* pa, const float* pb, F8& a, F8& b) {
    asm volatile("s_load_dwordx8 %0, %2, 0x0\n\t"
                 "s_load_dwordx8 %1, %3, 0x0\n\t"
                 "s_waitcnt lgkmcnt(0)"
                 : "=&s"(a), "=&s"(b) : "s"(pa), "s"(pb));
}
__device__ __forceinline__ F2 sld2(const float* p) {
    F2V r;
    asm volatile("s_load_dwordx2 %0, %1, 0x0\n\ts_waitcnt lgkmcnt(0)"
                 : "=s"(r) : "s"(p));
    return F2{r[0], r[1]};
}

// ---- packed fp32 complex primitives (VOP3P), coefficient operand in SGPRs ----
__device__ __forceinline__ F2 pk_mul_bl(F2 a, F2 u) {   // (a.x*u.x, a.y*u.x)
    F2 d;
    asm("v_pk_mul_f32 %0, %1, %2 op_sel:[0,0] op_sel_hi:[1,0]"
        : "=v"(d) : "v"(a), "s"(u));
    return d;
}
__device__ __forceinline__ void pk_cross(F2& d, F2 a, F2 u) {  // d += (-a.y*u.y, a.x*u.y)
    asm("v_pk_fma_f32 %0, %1, %2, %0 op_sel:[1,1,0] op_sel_hi:[0,1,1] neg_lo:[1,0,0]"
        : "+v"(d) : "v"(a), "s"(u));
}
__device__ __forceinline__ void pk_fma_bl(F2& d, F2 a, F2 u) { // d += (a.x*u.x, a.y*u.x)
    asm("v_pk_fma_f32 %0, %1, %2, %0 op_sel:[0,0,0] op_sel_hi:[1,0,1]"
        : "+v"(d) : "v"(a), "s"(u));
}
__device__ __forceinline__ void pk_swapneg(F2& d, F2 a, F2 cs) { // d += (a.y*cs.y, -a.x*cs.y)
    asm("v_pk_fma_f32 %0, %1, %2, %0 op_sel:[1,1,0] op_sel_hi:[0,1,1] neg_hi:[1,0,0]"
        : "+v"(d) : "v"(a), "s"(cs));
}
// all-VGPR variants (expv: both operands are lane data)
__device__ __forceinline__ void pk_fma(F2& d, F2 a, F2 b) {    // d += a*b
    asm("v_pk_fma_f32 %0, %1, %2, %0" : "+v"(d) : "v"(a), "v"(b));
}
__device__ __forceinline__ void pk_imacc(F2& d, F2 a0, F2 a1) { // d += (a0.x*a1.y, -a0.y*a1.x)
    asm("v_pk_fma_f32 %0, %1, %2, %0 op_sel:[0,1,0] op_sel_hi:[1,0,1] neg_hi:[1,0,0]"
        : "+v"(d) : "v"(a0), "v"(a1));
}
__device__ __forceinline__ F2 pk_cmul(F2 u, F2 a) {
    F2 d = pk_mul_bl(a, u);
    pk_cross(d, a, u);
    return d;
}
__device__ __forceinline__ void pk_cfma(F2& d, F2 u, F2 a) {
    pk_fma_bl(d, a, u);
    pk_cross(d, a, u);
}

// ---- VALU-only wave sum via DPP (classic gfx9 chain). Total lands in
// lane 63; bound_ctrl=true zeroes invalid-lane reads (safe for sum).
__device__ __forceinline__ float wsum(float x) {
#define DPPADD(ctrl) \
    x += __builtin_bit_cast(float, __builtin_amdgcn_update_dpp( \
             0, __builtin_bit_cast(int, x), (ctrl), 0xf, 0xf, true))
    DPPADD(0x111);   // row_shr:1
    DPPADD(0x112);   // row_shr:2
    DPPADD(0x114);   // row_shr:4
    DPPADD(0x118);   // row_shr:8  -> lane r*16+15 = row sum
    DPPADD(0x142);   // row_bcast15 -> lane31 = r0+r1, lane63 = r2+r3
    DPPADD(0x143);   // row_bcast31 -> lane63 = total
#undef DPPADD
    return __builtin_bit_cast(float, __builtin_amdgcn_readlane(
               __builtin_bit_cast(int, x), 63));
}

__device__ __forceinline__ void build_u(float tx, float ty, float tz, float* u) {
    float sx = sinf(0.5f*tx), cx = cosf(0.5f*tx);
    float sy = sinf(0.5f*ty), cy = cosf(0.5f*ty);
    float sz = sinf(0.5f*tz), cz = cosf(0.5f*tz);
    float A00r = cy*cx, A00i =  sy*sx;     // A = Ry*Rx
    float A01r = -sy*cx, A01i = -cy*sx;
    float A10r =  sy*cx, A10i = -cy*sx;
    float A11r =  cy*cx, A11i = -sy*sx;
    // U = Rz*A: row0 *= (cz - i sz), row1 *= (cz + i sz)   [verified r1/3/5..21]
    u[0] = cz*A00r + sz*A00i;  u[1] = cz*A00i - sz*A00r;
    u[2] = cz*A01r + sz*A01i;  u[3] = cz*A01i - sz*A01r;
    u[4] = cz*A10r - sz*A10i;  u[5] = cz*A10i + sz*A10r;
    u[6] = cz*A11r - sz*A11i;  u[7] = cz*A11i + sz*A11r;
}

// coef layout (floats): [0..95] U0 plain (q*8); [96..191] RX(ang[36+q-1])*U0[q] (q=1..11);
// [192..287] U1 plain; [288..295] U1[0]*RX(ang[47]); [296..319] L1 CRX (cos,sin)[c=0..11]
__global__ void prep_kernel(const float* __restrict__ ang, float* __restrict__ coef) {
    int t = threadIdx.x;
    if (t < 12) {
        float u[8]; build_u(ang[t], ang[12+t], ang[24+t], u);
#pragma unroll
        for (int j = 0; j < 8; ++j) coef[t*8 + j] = u[j];
    } else if (t < 24) {
        int q = t - 12;
        float u[8]; build_u(ang[48+q], ang[60+q], ang[72+q], u);
#pragma unroll
        for (int j = 0; j < 8; ++j) coef[192 + q*8 + j] = u[j];
    } else if (t < 36) {
        int c = t - 24;
        float th = 0.5f * ang[95 - c];     // L1 ring gate (c,c+1) = tape slot 84+(11-c)
        coef[296 + c*2]     = cosf(th);
        coef[296 + c*2 + 1] = sinf(th);
    } else if (t < 47) {
        int q = t - 35;                    // 1..11: M = RX(ang[36+q-1]) * U0[q]
        float u[8]; build_u(ang[q], ang[12+q], ang[24+q], u);
        float c = cosf(0.5f*ang[36+q-1]), s = sinf(0.5f*ang[36+q-1]);
        float m[8];
        m[0] = c*u[0] + s*u[5];  m[1] = c*u[1] - s*u[4];   // M00 = c u00 - i s u10
        m[2] = c*u[2] + s*u[7];  m[3] = c*u[3] - s*u[6];   // M01 = c u01 - i s u11
        m[4] = s*u[1] + c*u[4];  m[5] = -s*u[0] + c*u[5];  // M10 = -i s u00 + c u10
        m[6] = s*u[3] + c*u[6];  m[7] = -s*u[2] + c*u[7];  // M11 = -i s u01 + c u11
#pragma unroll
        for (int j = 0; j < 8; ++j) coef[96 + q*8 + j] = m[j];
    } else if (t == 47) {                  // M = U1[0] * RX(ang[47])  [CR0(11,0) then U1(0)]
        float u[8]; build_u(ang[48], ang[60], ang[72], u);
        float c = cosf(0.5f*ang[47]), s = sinf(0.5f*ang[47]);
        float m[8];
        m[0] = c*u[0] + s*u[3];  m[1] = c*u[1] - s*u[2];   // M00 = c u00 - i s u01
        m[2] = s*u[1] + c*u[2];  m[3] = -s*u[0] + c*u[3];  // M01 = -i s u00 + c u01
        m[4] = c*u[4] + s*u[7];  m[5] = c*u[5] - s*u[6];   // M10 = c u10 - i s u11
        m[6] = s*u[5] + c*u[6];  m[7] = -s*u[4] + c*u[7];  // M11 = -i s u10 + c u11
#pragma unroll
        for (int j = 0; j < 8; ++j) coef[288 + j] = m[j];
    }
}

// ---- register-part (compile-time per unrolled r) of each packing ----
__device__ __forceinline__ int rpA1(int r) {   // T1/T6, A side (a8 deleted = r&1)
    int a11=(r>>3)&1, a10=(r>>2)&1, a9=(r>>1)&1;
    return (a11<<8)|(a10<<7)|(a9<<6)|(a11<<3)|(a10<<2)|(a9<<1)|(a9<<0);
}
__device__ __forceinline__ int rpB1(int r) {   // T1/T6, B side
    int a5=(r>>1)&1, a7=(r>>2)&1, a6=(r>>3)&1;
    return (a7<<5)|(a6<<4)|(a7<<3)|(a6<<2)|(a5<<0);
}
__device__ __forceinline__ int rpB2(int r) {   // T2, B side (a5 deleted = r&2)
    int a8=r&1, a7=(r>>2)&1, a6=(r>>3)&1;
    return (a8<<5)|(a7<<4)|(a6<<3)|(a7<<2)|(a8<<1)|(a6<<0);
}
__device__ __forceinline__ int rpC2(int r) {   // T2, C side
    int a2=r&1, a4=(r>>2)&1, a3=(r>>3)&1;
    return (a3<<3)|(a2<<2)|(a4<<1);
}
__device__ __forceinline__ int rpC3(int r) {   // T3/T4, C/C' side (a2 deleted = r&1)
    int a5=(r>>1)&1, a4=(r>>2)&1, a3=(r>>3)&1;
    return (a5<<4)|(a3<<3)|(a4<<2)|(a5<<0);
}
__device__ __forceinline__ int rpD3(int r) {   // T3/T4, D side
    int a1=(r>>1)&1, a0=(r>>2)&1, a11=(r>>3)&1;
    return (a11<<8)|(a11<<3)|(a1<<1)|((a0^a11)<<0);
}
__device__ __forceinline__ int rpC5(int r) {   // T5, C' side (a5 deleted = r&2)
    int a2=r&1, a4=(r>>2)&1, a3=(r>>3)&1;
    return (a4<<4)|(a3<<3)|(a2<<2)|(a4<<0);
}
__device__ __forceinline__ int rpB5(int r) {   // T5, B' side
    int a8=r&1, a7=(r>>2)&1, a6=(r>>3)&1;
    return (a7<<10)|(a6<<9)|(a8<<5)|(a8<<3);
}

// ---- tile pointers (lane/wave part of each packing); scoped per transpose ----
#define LBITS \
    const int l0=l&1, l1=(l>>1)&1, l2=(l>>2)&1, l3=(l>>3)&1, l4=(l>>4)&1, \
              l5=(l>>5)&1, w0=w&1, w1=(w>>1)&1; \
    (void)l0;(void)l1;(void)l2;(void)l3;(void)l4;(void)l5;(void)w0;(void)w1;

__device__ __forceinline__ int tpA1f(int l, int w) { LBITS
    return (w1<<10)|(w0<<9)|(l5<<5)|(l4<<4)|((l1^l5)<<3)|((l0^l4)<<2)|(l2<<1)|(l3<<0); }
__device__ __forceinline__ int tpB1f(int l, int w) { LBITS
    return (w1<<10)|(w0<<9)|(l5<<8)|(l4<<7)|(l3<<6)|((l1^l5)<<3)|((l0^l4)<<2)|((l2^l3)<<1)|(l3<<0); }
__device__ __forceinline__ int tpC2f(int l, int w) { LBITS
    return (w1<<10)|(w0<<9)|(l5<<8)|(l4<<7)|(l3<<6)|(l2<<5)|(l1<<4)|((l5^l0)<<3)|((l4^l1)<<2)|((l3^l2)<<1)|((l0^l3)<<0); }
__device__ __forceinline__ int tpC3f(int l, int w) { LBITS
    return (l1<<10)|(l0<<9)|(l5<<8)|(l4<<7)|(l3<<6)|(l2<<5)|((l5^l4)<<3)|(l3<<2)|((w1^l2)<<1)|((w0^l5)<<0); }
__device__ __forceinline__ int tpD3f(int l, int w) { LBITS
    return (w1<<10)|(w0<<9)|(l5<<7)|(l4<<6)|(l3<<5)|(l2<<4)|((l0^l5)<<3)|((l1^l4)<<2)|(l3<<1)|(l2<<0); }
__device__ __forceinline__ int tpC4f(int l, int w) { LBITS
    return (w1<<10)|(w0<<9)|(l5<<8)|(l4<<7)|(l3<<6)|(l2<<5)|((l5^l4)<<3)|(l3<<2)|((l1^l2)<<1)|((l0^l5)<<0); }
__device__ __forceinline__ int tpC5f(int l, int w) { LBITS
    return (w1<<10)|(w0<<9)|(l5<<8)|(l4<<7)|(l3<<6)|(l2<<5)|((l5^l2)<<3)|(l4<<2)|((l1^l3)<<1)|(l0<<0); }
__device__ __forceinline__ int tpB5f(int l, int w) { LBITS
    return (l5<<8)|(l4<<7)|(l3<<6)|(l2<<4)|((l1^l5)<<3)|((l0^l4)<<2)|((w1^l3)<<1)|((w0^l2)<<0); }

// Plain 1q gate over subset {r0: (r0&M)==0, (S1==0 || (r0&S1)==H1)};
// coefficients in SGPRs.
template<int M, int S1, int H1>
__device__ __forceinline__ void g1q(F2* amp, F2 u00, F2 u01, F2 u10, F2 u11) {
#pragma unroll
    for (int r0 = 0; r0 < 16; ++r0) {
        if (r0 & M) continue;
        if (S1 != 0 && (r0 & S1) != H1) continue;
        const int r1 = r0 + M;
        F2 a0 = amp[r0], a1 = amp[r1];
        F2 n0 = pk_cmul(u00, a0); pk_cfma(n0, u01, a1);
        F2 n1 = pk_cmul(u10, a0); pk_cfma(n1, u11, a1);
        amp[r0] = n0; amp[r1] = n1;
    }
}
template<int M, int S1, int H1>
__device__ __forceinline__ void g1qF(F2* amp, F8 u) {
    g1q<M, S1, H1>(amp, F2{u[0],u[1]}, F2{u[2],u[3]}, F2{u[4],u[5]}, F2{u[6],u[7]});
}

// Fused gate: matrix selected per pair by compile-time control bit MSEL.
template<int MSEL, int M, int S1, int H1>
__device__ __forceinline__ void fg1q(F2* amp, F2 a00, F2 a01, F2 a10, F2 a11,
                                     F2 b00, F2 b01, F2 b10, F2 b11) {
#pragma unroll
    for (int r0 = 0; r0 < 16; ++r0) {
        if (r0 & M) continue;
        if (S1 != 0 && (r0 & S1) != H1) continue;
        const int r1 = r0 + M;
        const bool sel = (r0 & MSEL) != 0;           // compile-time
        F2 u00 = sel ? b00 : a00, u01 = sel ? b01 : a01;
        F2 u10 = sel ? b10 : a10, u11 = sel ? b11 : a11;
        F2 a0 = amp[r0], a1 = amp[r1];
        F2 n0 = pk_cmul(u00, a0); pk_cfma(n0, u01, a1);
        F2 n1 = pk_cmul(u10, a0); pk_cfma(n1, u11, a1);
        amp[r0] = n0; amp[r1] = n1;
    }
}
template<int MSEL, int M, int S1, int H1>
__device__ __forceinline__ void fg1qF(F2* amp, F8 a, F8 b) {
    fg1q<MSEL, M, S1, H1>(amp,
        F2{a[0],a[1]}, F2{a[2],a[3]}, F2{a[4],a[5]}, F2{a[6],a[7]},
        F2{b[0],b[1]}, F2{b[2],b[3]}, F2{b[4],b[5]}, F2{b[6],b[7]});
}

template<int MC, int MT>
__device__ __forceinline__ void crx(F2* amp, F2 cs) {   // cs in SGPRs
#pragma unroll
    for (int r0 = 0; r0 < 16; ++r0) {
        if (!(r0 & MC) || (r0 & MT)) continue;
        const int r1 = r0 + MT;
        F2 a0 = amp[r0], a1 = amp[r1];
        F2 n0 = pk_mul_bl(a0, cs); pk_swapneg(n0, a1, cs);
        F2 n1 = pk_mul_bl(a1, cs); pk_swapneg(n1, a0, cs);
        amp[r0] = n0; amp[r1] = n1;
    }
}

// expv with DPP wave-sum (no LDS-pipe shuffles)
template<int M>
__device__ __forceinline__ void expv(const F2* amp, int q, int lane,
                                     float& fx, float& fy, float& fz) {
    F2 zp = {0.f, 0.f}, zm = {0.f, 0.f}, xp = {0.f, 0.f}, ip = {0.f, 0.f};
#pragma unroll
    for (int r0 = 0; r0 < 16; ++r0) {
        if (r0 & M) continue;
        const int r1 = r0 + M;
        F2 a0 = amp[r0], a1 = amp[r1];
        pk_fma(zp, a0, a0);
        pk_fma(zm, a1, a1);
        pk_fma(xp, a0, a1);
        pk_imacc(ip, a0, a1);
    }
    float zz = (zp.x + zp.y) - (zm.x + zm.y);
    float xr = 2.f * (xp.x + xp.y);
    float xi = 2.f * (ip.x + ip.y);
    float txr = wsum(xr);
    float txi = wsum(xi);
    float tzz = wsum(zz);
    if (lane == q) { fx = txr; fy = txi; fz = tzz; }
}

// enumerate j-th pair base r0 with (r0 & M)==0 and (r0 & SB)==hb*SB (4-bit regs)
template<int M, int SB>
__device__ __forceinline__ int r0_of(int j, int hb) {
    int r = hb ? SB : 0, b = 1;
#pragma unroll
    for (int p = 0; p < 4; ++p) {
        const int mm = 1 << p;
        if (mm == M || mm == SB) continue;
        if (j & b) r |= mm;
        b <<= 1;
    }
    return r;
}

// Store one half (8 regs with (r & SB) == HB).
#define ST_T(TP, RP, SB, HB) \
  { _Pragma("unroll") for (int r = 0; r < 16; ++r) { \
      if ((r & (SB)) != (HB)) continue; \
      psi[(TP) ^ RP(r)] = amp[r]; } }
// Load one half in pair order of the next gate (mask M).
#define LD_T(TP, RP, M, SB, HB) \
  { _Pragma("unroll") for (int k = 0; k < 8; ++k) { \
      const int j = k >> 1; \
      const int r0 = r0_of<M, SB>(j, (HB) != 0); \
      const int r = (k & 1) ? (r0 + (M)) : r0; \
      amp[r] = psi[(TP) ^ RP(r)]; } }

#define U0P(q, M)    g1qF<M, 0, 0>(amp, sld8(cf + (q)*8))
#define FU0(q, MS, M) do { F8 ua_, ub_; sld16(cf + (q)*8, cf + 96 + (q)*8, ua_, ub_); \
                           fg1qF<MS, M, 0, 0>(amp, ua_, ub_); } while(0)
#define U1P(q, M)    g1qF<M, 0, 0>(amp, sld8(cf + 192 + (q)*8))
#define FU1_0()      do { F8 ua_, ub_; sld16(cf + 192, cf + 288, ua_, ub_); \
                          fg1qF<4, 8, 0, 0>(amp, ua_, ub_); } while(0)
#define CR1(c, MC, MT) crx<MC, MT>(amp, sld2(cf + 296 + (c)*2))
#define EXPV(q, M)   expv<M>(amp, q, l, fx, fy, fz)

__global__ __launch_bounds__(256, 1)
void qsim_kernel(const float* __restrict__ sv,      // [B, 4096]
                 const float* __restrict__ cf,      // [320] precomputed coefficients
                 const float* __restrict__ W,       // [10, 36]
                 const float* __restrict__ bvec,    // [10]
                 float* __restrict__ out)           // [B, 10]
{
    __shared__ F2 psi[2048];         // 16 KB split-transpose buffer
    const int t = threadIdx.x;
    const int b = blockIdx.x;
    const int l = t & 63, w = t >> 6;

    F2 amp[16];
    const float* svb = sv + (size_t)b * DIM;
    // layout A: idx = r<<8 | l<<2 | w; pair order for U0P(0, M=8)
#pragma unroll
    for (int k = 0; k < 16; ++k) {
        const int r = (k & 1) ? ((k >> 1) + 8) : (k >> 1);
        amp[r] = make_float2(svb[(r << 8) | (l << 2) | w], 0.f);
    }

    float fx = 0.f, fy = 0.f, fz = 0.f;

    // ---- A {q0:8 q1:4 q2:2 q3:1}: U0(0); [U0;CR0] q=1..3 ----
    U0P(0, 8);
    FU0(1, 8, 4); FU0(2, 4, 2); FU0(3, 2, 1);

    // ---- T1 A->B (internal, del a8, SB=1): halfgate FU0(4,1,4) ----
    {
        F8 ua, ub; sld16(cf + 4*8, cf + 96 + 4*8, ua, ub);
        const int tpA = tpA1f(l, w), tpB = tpB1f(l, w);
        ST_T(tpA, rpA1, 1, 0);
        LD_T(tpB, rpB1, 4, 1, 0);
        ST_T(tpA, rpA1, 1, 1);
        fg1qF<1, 4, 1, 0>(amp, ua, ub);
        LD_T(tpB, rpB1, 4, 1, 1);
        fg1qF<1, 4, 1, 1>(amp, ua, ub);
    }
    // ---- B {q3:1 q4:4 q5:8 q6:2} ----
    FU0(5, 4, 8); FU0(6, 8, 2);

    // ---- T2 B->C (internal, del a5, SB=2): halfgate FU0(7,2,4) ----
    {
        F8 ua, ub; sld16(cf + 7*8, cf + 96 + 7*8, ua, ub);
        const int tpB = tpB1f(l, w), tpC = tpC2f(l, w);
        ST_T(tpB, rpB2, 2, 0);
        LD_T(tpC, rpC2, 4, 2, 0);
        ST_T(tpB, rpB2, 2, 2);
        fg1qF<2, 4, 2, 0>(amp, ua, ub);
        LD_T(tpC, rpC2, 4, 2, 2);
        fg1qF<2, 4, 2, 2>(amp, ua, ub);
    }
    // ---- C {q6:2 q7:4 q8:8 q9:1} ----
    FU0(8, 4, 8); FU0(9, 8, 1);

    // ---- T3 C->D (CROSS, del a2, SB=1): halfgate FU0(10,1,2) ----
    {
        F8 ua, ub; sld16(cf + 10*8, cf + 96 + 10*8, ua, ub);
        __syncthreads();             // T2 slots not wave-disjoint vs T3 stores
        const int tpC = tpC3f(l, w), tpD = tpD3f(l, w);
        ST_T(tpC, rpC3, 1, 0);
        __syncthreads();
        LD_T(tpD, rpD3, 2, 1, 0);
        __syncthreads();
        ST_T(tpC, rpC3, 1, 1);
        fg1qF<1, 2, 1, 0>(amp, ua, ub);
        __syncthreads();
        LD_T(tpD, rpD3, 2, 1, 1);
        fg1qF<1, 2, 1, 1>(amp, ua, ub);
    }
    // ---- D {q9:1 q10:2 q11:4 q0:8}: [CR0(11,0);U1(0)]; U1(9..11);
    //      L1 ring (11,0),(10,11),(9,10); expv 10,11 ----
    FU0(11, 2, 4);
    FU1_0();
    U1P(9, 1); U1P(10, 2); U1P(11, 4);
    CR1(11, 4, 8); CR1(10, 2, 4); CR1(9, 1, 2);
    EXPV(10, 2); EXPV(11, 4);

    // ---- T4 D->C' (internal, del a2, SB=1): halfgate U1P(7,4) ----
    // no barrier: T3-LD and T4-ST slots both carry a7a6=wave at f10,f9
    {
        F8 u7 = sld8(cf + 192 + 7*8);
        const int tpD = tpD3f(l, w), tpC = tpC4f(l, w);
        ST_T(tpD, rpD3, 1, 0);
        LD_T(tpC, rpC3, 4, 1, 0);
        ST_T(tpD, rpD3, 1, 1);
        g1qF<4, 1, 0>(amp, u7);
        LD_T(tpC, rpC3, 4, 1, 1);
        g1qF<4, 1, 1>(amp, u7);
    }
    // ---- C' {q6:2 q7:4 q8:8 q9:1}: U1(6,8); ring (8,9),(7,8),(6,7); expv 7,8,9 ----
    U1P(6, 2); U1P(8, 8);
    CR1(8, 8, 1); CR1(7, 4, 8); CR1(6, 2, 4);
    EXPV(9, 1); EXPV(8, 8); EXPV(7, 4);

    // ---- T5 C'->B' (CROSS, del a5, SB=2): halfgate U1P(3,1) ----
    // no leading barrier: T4-LD and T5-ST slots both carry a7a6=wave at f10,f9
    {
        F8 u3 = sld8(cf + 192 + 3*8);
        const int tpC = tpC5f(l, w), tpB = tpB5f(l, w);
        ST_T(tpC, rpC5, 2, 0);
        __syncthreads();
        LD_T(tpB, rpB5, 1, 2, 0);
        __syncthreads();
        ST_T(tpC, rpC5, 2, 2);
        g1qF<1, 2, 0>(amp, u3);
        __syncthreads();
        LD_T(tpB, rpB5, 1, 2, 2);
        g1qF<1, 2, 2>(amp, u3);
        __syncthreads();             // protect cross-wave reads from T6 stores
    }
    // ---- B' {q3:1 q4:4 q5:8 q6:2}: U1(4,5); ring (5,6),(4,5),(3,4); expv 4,5,6 ----
    U1P(4, 4); U1P(5, 8);
    CR1(5, 8, 2); CR1(4, 4, 8); CR1(3, 1, 4);
    EXPV(6, 2); EXPV(5, 8); EXPV(4, 4);

    // ---- T6 B'->A' (internal, del a8, SB=1): halfgate U1P(1,4) ----
    {
        F8 u1 = sld8(cf + 192 + 1*8);
        const int tpB = tpB1f(l, w), tpA = tpA1f(l, w);
        ST_T(tpB, rpB1, 1, 0);
        LD_T(tpA, rpA1, 4, 1, 0);
        ST_T(tpB, rpB1, 1, 1);
        g1qF<4, 1, 0>(amp, u1);
        LD_T(tpA, rpA1, 4, 1, 1);
        g1qF<4, 1, 1>(amp, u1);
    }
    // ---- A' {q0:8 q1:4 q2:2 q3:1}: U1(2); ring (2,3),(1,2),(0,1); expv 0..3 ----
    U1P(2, 2);
    CR1(2, 2, 1); CR1(1, 4, 2); CR1(0, 8, 4);
    EXPV(3, 1); EXPV(2, 2); EXPV(1, 4); EXPV(0, 8);

    // ---- combine 4 waves' partial features ----
    __syncthreads();                 // psi dead only after all waves' T6 loads
    float* fbuf = (float*)psi;       // [4][36]
    if (l < 12) {
        fbuf[w * 36 + l]      = fx;
        fbuf[w * 36 + 12 + l] = fy;
        fbuf[w * 36 + 24 + l] = fz;
    }
    __syncthreads();
    if (t < 10) {
        float a = bvec[t];
#pragma unroll
        for (int f = 0; f < 36; ++f)
            a += W[t * 36 + f] * (fbuf[f] + fbuf[36 + f] + fbuf[72 + f] + fbuf[108 + f]);
        out[(size_t)b * 10 + t] = a;
    }
}

extern "C" void kernel_launch(void* const* d_in, const int* in_sizes, int n_in,
                              void* d_out, int out_size, void* d_ws, size_t ws_size,
                              hipStream_t stream) {
    const float* sv     = (const float*)d_in[0];
    const float* angles = (const float*)d_in[1];
    const float* W      = (const float*)d_in[2];
    const float* bvec   = (const float*)d_in[3];
    float* out  = (float*)d_out;
    float* coef = (float*)d_ws;      // 320 floats of scratch
    int batch = in_sizes[0] / DIM;   // 2048
    prep_kernel<<<1, 64, 0, stream>>>(angles, coef);
    qsim_kernel<<<batch, 256, 0, stream>>>(sv, coef, W, bvec, out);
}

// Round 10
// 125.224 us; speedup vs baseline: 1.1799x; 1.0183x over previous
//
#include <hip/hip_runtime.h>

#define DIM 4096
using F2 = float2;
using F8 = __attribute__((ext_vector_type(8))) float;
using F2V = __attribute__((ext_vector_type(2))) float;

// R23 = R22 (champion, qsim 60.8 us, VGPR 60, VALUBusy 65%) + three provable
// VALU trims (~6% of pk work):
//  (1) zp-trick: states normalized + gates unitary => Z_q = 2*Sum|a0|^2 - 1.
//      Drop the zm accumulator in expv (-96 pk/wave); fold the -1 and the
//      2x feature scaling into the 10-thread final combine.
//  (2) expv stores raw partials (no 2.f* mults).
//  (3) real-input first gate: input sv is real (imag=0) -> U0(0) needs
//      4 pk/pair not 8 via pk_smul/pk_sfma (= proven pk_mul_bl/pk_fma_bl
//      opcodes+modifiers with "v"/"s" constraints swapped; -32 pk/wave).
// Everything else byte-identical to R22 (harness-verified 7x).
// R22 forensics: bank conflicts EXACTLY unchanged after shuffle removal ->
// conflicts live in transposes; b128 packing impossible under 16KB split
// (only shared reg bit per transition IS the deleted split bit); cross
// transposes structurally minimal (2).
//
// Address bits: qubit q <-> a[11-q]. Layouts (reg bit value in parens):
//  A : regs a11(8) a10(4) a9(2) a8(1); lanes a7..a2=l5..l0; wave a1a0
//      masks: q0:8 q1:4 q2:2 q3:1
//  B : regs a8(1) a7(4) a6(8) a5(2); lanes a11,a10,a9,a4,a3,a2=l5..l0; wave a1a0
//      masks: q3:1 q4:4 q5:8 q6:2
//  C : regs a5(2) a4(4) a3(8) a2(1); lanes a11..a6=l5..l0; wave a1a0
//      masks: q6:2 q7:4 q8:8 q9:1
//  D : regs a2(1) a1(2) a0(4) a11(8); lanes a10,a9,a8,a5,a4,a3=l5..l0; wave a7a6
//      masks: q9:1 q10:2 q11:4 q0:8
//  C': regs as C; lanes a11,a10,a9,a8,a1,a0=l5..l0; wave a7a6
//  B': = B.   A': = A.
// Transitions: T1 A->B del a8 SB=1 internal; T2 B->C del a5 SB=2 internal;
//  T3 C->D del a2 SB=1 CROSS; T4 D->C' del a2 SB=1 internal;
//  T5 C'->B' del a5 SB=2 CROSS; T6 B'->A' del a8 SB=1 internal.
// __launch_bounds__(256,1): min_waves>=6 coerces allocator into amp[]
// scratch spill (R16-R18 forensics); (.,1) never spilled.

// ---- scalar coefficient loads (SMEM) ----
__device__ __forceinline__ F8 sld8(const float* p) {
    F8 r;
    asm volatile("s_load_dwordx8 %0, %1, 0x0\n\ts_waitcnt lgkmcnt(0)"
                 : "=s"(r) : "s"(p));
    return r;
}
__device__ __forceinline__ void sld16(const float* pa, const float* pb, F8& a, F8& b) {
    asm volatile("s_load_dwordx8 %0, %2, 0x0\n\t"
                 "s_load_dwordx8 %1, %3, 0x0\n\t"
                 "s_waitcnt lgkmcnt(0)"
                 : "=&s"(a), "=&s"(b) : "s"(pa), "s"(pb));
}
__device__ __forceinline__ F2 sld2(const float* p) {
    F2V r;
    asm volatile("s_load_dwordx2 %0, %1, 0x0\n\ts_waitcnt lgkmcnt(0)"
                 : "=s"(r) : "s"(p));
    return F2{r[0], r[1]};
}

// ---- packed fp32 complex primitives (VOP3P), coefficient operand in SGPRs ----
__device__ __forceinline__ F2 pk_mul_bl(F2 a, F2 u) {   // (a.x*u.x, a.y*u.x)
    F2 d;
    asm("v_pk_mul_f32 %0, %1, %2 op_sel:[0,0] op_sel_hi:[1,0]"
        : "=v"(d) : "v"(a), "s"(u));
    return d;
}
__device__ __forceinline__ void pk_cross(F2& d, F2 a, F2 u) {  // d += (-a.y*u.y, a.x*u.y)
    asm("v_pk_fma_f32 %0, %1, %2, %0 op_sel:[1,1,0] op_sel_hi:[0,1,1] neg_lo:[1,0,0]"
        : "+v"(d) : "v"(a), "s"(u));
}
__device__ __forceinline__ void pk_fma_bl(F2& d, F2 a, F2 u) { // d += (a.x*u.x, a.y*u.x)
    asm("v_pk_fma_f32 %0, %1, %2, %0 op_sel:[0,0,0] op_sel_hi:[1,0,1]"
        : "+v"(d) : "v"(a), "s"(u));
}
__device__ __forceinline__ void pk_swapneg(F2& d, F2 a, F2 cs) { // d += (a.y*cs.y, -a.x*cs.y)
    asm("v_pk_fma_f32 %0, %1, %2, %0 op_sel:[1,1,0] op_sel_hi:[0,1,1] neg_hi:[1,0,0]"
        : "+v"(d) : "v"(a), "s"(cs));
}
// swapped-constraint twins for the REAL-input first gate:
// u (SGPR pair) scaled by lane-real s.x — same opcode/modifiers as the
// proven pk_mul_bl/pk_fma_bl, operands v/s exchanged.
__device__ __forceinline__ F2 pk_smul(F2 u, F2 s) {    // (u.x*s.x, u.y*s.x)
    F2 d;
    asm("v_pk_mul_f32 %0, %1, %2 op_sel:[0,0] op_sel_hi:[1,0]"
        : "=v"(d) : "s"(u), "v"(s));
    return d;
}
__device__ __forceinline__ void pk_sfma(F2& d, F2 u, F2 s) { // d += (u.x*s.x, u.y*s.x)
    asm("v_pk_fma_f32 %0, %1, %2, %0 op_sel:[0,0,0] op_sel_hi:[1,0,1]"
        : "+v"(d) : "s"(u), "v"(s));
}
// all-VGPR variants (expv: both operands are lane data)
__device__ __forceinline__ void pk_fma(F2& d, F2 a, F2 b) {    // d += a*b
    asm("v_pk_fma_f32 %0, %1, %2, %0" : "+v"(d) : "v"(a), "v"(b));
}
__device__ __forceinline__ void pk_imacc(F2& d, F2 a0, F2 a1) { // d += (a0.x*a1.y, -a0.y*a1.x)
    asm("v_pk_fma_f32 %0, %1, %2, %0 op_sel:[0,1,0] op_sel_hi:[1,0,1] neg_hi:[1,0,0]"
        : "+v"(d) : "v"(a0), "v"(a1));
}
__device__ __forceinline__ F2 pk_cmul(F2 u, F2 a) {
    F2 d = pk_mul_bl(a, u);
    pk_cross(d, a, u);
    return d;
}
__device__ __forceinline__ void pk_cfma(F2& d, F2 u, F2 a) {
    pk_fma_bl(d, a, u);
    pk_cross(d, a, u);
}

// ---- VALU-only wave sum via DPP (proven R22). Total lands in lane 63. ----
__device__ __forceinline__ float wsum(float x) {
#define DPPADD(ctrl) \
    x += __builtin_bit_cast(float, __builtin_amdgcn_update_dpp( \
             0, __builtin_bit_cast(int, x), (ctrl), 0xf, 0xf, true))
    DPPADD(0x111);   // row_shr:1
    DPPADD(0x112);   // row_shr:2
    DPPADD(0x114);   // row_shr:4
    DPPADD(0x118);   // row_shr:8  -> lane r*16+15 = row sum
    DPPADD(0x142);   // row_bcast15 -> lane31 = r0+r1, lane63 = r2+r3
    DPPADD(0x143);   // row_bcast31 -> lane63 = total
#undef DPPADD
    return __builtin_bit_cast(float, __builtin_amdgcn_readlane(
               __builtin_bit_cast(int, x), 63));
}

__device__ __forceinline__ void build_u(float tx, float ty, float tz, float* u) {
    float sx = sinf(0.5f*tx), cx = cosf(0.5f*tx);
    float sy = sinf(0.5f*ty), cy = cosf(0.5f*ty);
    float sz = sinf(0.5f*tz), cz = cosf(0.5f*tz);
    float A00r = cy*cx, A00i =  sy*sx;     // A = Ry*Rx
    float A01r = -sy*cx, A01i = -cy*sx;
    float A10r =  sy*cx, A10i = -cy*sx;
    float A11r =  cy*cx, A11i = -sy*sx;
    // U = Rz*A: row0 *= (cz - i sz), row1 *= (cz + i sz)   [verified r1/3/5..22]
    u[0] = cz*A00r + sz*A00i;  u[1] = cz*A00i - sz*A00r;
    u[2] = cz*A01r + sz*A01i;  u[3] = cz*A01i - sz*A01r;
    u[4] = cz*A10r - sz*A10i;  u[5] = cz*A10i + sz*A10r;
    u[6] = cz*A11r - sz*A11i;  u[7] = cz*A11i + sz*A11r;
}

// coef layout (floats): [0..95] U0 plain (q*8); [96..191] RX(ang[36+q-1])*U0[q] (q=1..11);
// [192..287] U1 plain; [288..295] U1[0]*RX(ang[47]); [296..319] L1 CRX (cos,sin)[c=0..11]
__global__ void prep_kernel(const float* __restrict__ ang, float* __restrict__ coef) {
    int t = threadIdx.x;
    if (t < 12) {
        float u[8]; build_u(ang[t], ang[12+t], ang[24+t], u);
#pragma unroll
        for (int j = 0; j < 8; ++j) coef[t*8 + j] = u[j];
    } else if (t < 24) {
        int q = t - 12;
        float u[8]; build_u(ang[48+q], ang[60+q], ang[72+q], u);
#pragma unroll
        for (int j = 0; j < 8; ++j) coef[192 + q*8 + j] = u[j];
    } else if (t < 36) {
        int c = t - 24;
        float th = 0.5f * ang[95 - c];     // L1 ring gate (c,c+1) = tape slot 84+(11-c)
        coef[296 + c*2]     = cosf(th);
        coef[296 + c*2 + 1] = sinf(th);
    } else if (t < 47) {
        int q = t - 35;                    // 1..11: M = RX(ang[36+q-1]) * U0[q]
        float u[8]; build_u(ang[q], ang[12+q], ang[24+q], u);
        float c = cosf(0.5f*ang[36+q-1]), s = sinf(0.5f*ang[36+q-1]);
        float m[8];
        m[0] = c*u[0] + s*u[5];  m[1] = c*u[1] - s*u[4];   // M00 = c u00 - i s u10
        m[2] = c*u[2] + s*u[7];  m[3] = c*u[3] - s*u[6];   // M01 = c u01 - i s u11
        m[4] = s*u[1] + c*u[4];  m[5] = -s*u[0] + c*u[5];  // M10 = -i s u00 + c u10
        m[6] = s*u[3] + c*u[6];  m[7] = -s*u[2] + c*u[7];  // M11 = -i s u01 + c u11
#pragma unroll
        for (int j = 0; j < 8; ++j) coef[96 + q*8 + j] = m[j];
    } else if (t == 47) {                  // M = U1[0] * RX(ang[47])  [CR0(11,0) then U1(0)]
        float u[8]; build_u(ang[48], ang[60], ang[72], u);
        float c = cosf(0.5f*ang[47]), s = sinf(0.5f*ang[47]);
        float m[8];
        m[0] = c*u[0] + s*u[3];  m[1] = c*u[1] - s*u[2];   // M00 = c u00 - i s u01
        m[2] = s*u[1] + c*u[2];  m[3] = -s*u[0] + c*u[3];  // M01 = -i s u00 + c u01
        m[4] = c*u[4] + s*u[7];  m[5] = c*u[5] - s*u[6];   // M10 = c u10 - i s u11
        m[6] = s*u[5] + c*u[6];  m[7] = -s*u[4] + c*u[7];  // M11 = -i s u10 + c u11
#pragma unroll
        for (int j = 0; j < 8; ++j) coef[288 + j] = m[j];
    }
}

// ---- register-part (compile-time per unrolled r) of each packing ----
__device__ __forceinline__ int rpA1(int r) {   // T1/T6, A side (a8 deleted = r&1)
    int a11=(r>>3)&1, a10=(r>>2)&1, a9=(r>>1)&1;
    return (a11<<8)|(a10<<7)|(a9<<6)|(a11<<3)|(a10<<2)|(a9<<1)|(a9<<0);
}
__device__ __forceinline__ int rpB1(int r) {   // T1/T6, B side
    int a5=(r>>1)&1, a7=(r>>2)&1, a6=(r>>3)&1;
    return (a7<<5)|(a6<<4)|(a7<<3)|(a6<<2)|(a5<<0);
}
__device__ __forceinline__ int rpB2(int r) {   // T2, B side (a5 deleted = r&2)
    int a8=r&1, a7=(r>>2)&1, a6=(r>>3)&1;
    return (a8<<5)|(a7<<4)|(a6<<3)|(a7<<2)|(a8<<1)|(a6<<0);
}
__device__ __forceinline__ int rpC2(int r) {   // T2, C side
    int a2=r&1, a4=(r>>2)&1, a3=(r>>3)&1;
    return (a3<<3)|(a2<<2)|(a4<<1);
}
__device__ __forceinline__ int rpC3(int r) {   // T3/T4, C/C' side (a2 deleted = r&1)
    int a5=(r>>1)&1, a4=(r>>2)&1, a3=(r>>3)&1;
    return (a5<<4)|(a3<<3)|(a4<<2)|(a5<<0);
}
__device__ __forceinline__ int rpD3(int r) {   // T3/T4, D side
    int a1=(r>>1)&1, a0=(r>>2)&1, a11=(r>>3)&1;
    return (a11<<8)|(a11<<3)|(a1<<1)|((a0^a11)<<0);
}
__device__ __forceinline__ int rpC5(int r) {   // T5, C' side (a5 deleted = r&2)
    int a2=r&1, a4=(r>>2)&1, a3=(r>>3)&1;
    return (a4<<4)|(a3<<3)|(a2<<2)|(a4<<0);
}
__device__ __forceinline__ int rpB5(int r) {   // T5, B' side
    int a8=r&1, a7=(r>>2)&1, a6=(r>>3)&1;
    return (a7<<10)|(a6<<9)|(a8<<5)|(a8<<3);
}

// ---- tile pointers (lane/wave part of each packing); scoped per transpose ----
#define LBITS \
    const int l0=l&1, l1=(l>>1)&1, l2=(l>>2)&1, l3=(l>>3)&1, l4=(l>>4)&1, \
              l5=(l>>5)&1, w0=w&1, w1=(w>>1)&1; \
    (void)l0;(void)l1;(void)l2;(void)l3;(void)l4;(void)l5;(void)w0;(void)w1;

__device__ __forceinline__ int tpA1f(int l, int w) { LBITS
    return (w1<<10)|(w0<<9)|(l5<<5)|(l4<<4)|((l1^l5)<<3)|((l0^l4)<<2)|(l2<<1)|(l3<<0); }
__device__ __forceinline__ int tpB1f(int l, int w) { LBITS
    return (w1<<10)|(w0<<9)|(l5<<8)|(l4<<7)|(l3<<6)|((l1^l5)<<3)|((l0^l4)<<2)|((l2^l3)<<1)|(l3<<0); }
__device__ __forceinline__ int tpC2f(int l, int w) { LBITS
    return (w1<<10)|(w0<<9)|(l5<<8)|(l4<<7)|(l3<<6)|(l2<<5)|(l1<<4)|((l5^l0)<<3)|((l4^l1)<<2)|((l3^l2)<<1)|((l0^l3)<<0); }
__device__ __forceinline__ int tpC3f(int l, int w) { LBITS
    return (l1<<10)|(l0<<9)|(l5<<8)|(l4<<7)|(l3<<6)|(l2<<5)|((l5^l4)<<3)|(l3<<2)|((w1^l2)<<1)|((w0^l5)<<0); }
__device__ __forceinline__ int tpD3f(int l, int w) { LBITS
    return (w1<<10)|(w0<<9)|(l5<<7)|(l4<<6)|(l3<<5)|(l2<<4)|((l0^l5)<<3)|((l1^l4)<<2)|(l3<<1)|(l2<<0); }
__device__ __forceinline__ int tpC4f(int l, int w) { LBITS
    return (w1<<10)|(w0<<9)|(l5<<8)|(l4<<7)|(l3<<6)|(l2<<5)|((l5^l4)<<3)|(l3<<2)|((l1^l2)<<1)|((l0^l5)<<0); }
__device__ __forceinline__ int tpC5f(int l, int w) { LBITS
    return (w1<<10)|(w0<<9)|(l5<<8)|(l4<<7)|(l3<<6)|(l2<<5)|((l5^l2)<<3)|(l4<<2)|((l1^l3)<<1)|(l0<<0); }
__device__ __forceinline__ int tpB5f(int l, int w) { LBITS
    return (l5<<8)|(l4<<7)|(l3<<6)|(l2<<4)|((l1^l5)<<3)|((l0^l4)<<2)|((w1^l3)<<1)|((w0^l2)<<0); }

// Plain 1q gate over subset {r0: (r0&M)==0, (S1==0 || (r0&S1)==H1)};
// coefficients in SGPRs.
template<int M, int S1, int H1>
__device__ __forceinline__ void g1q(F2* amp, F2 u00, F2 u01, F2 u10, F2 u11) {
#pragma unroll
    for (int r0 = 0; r0 < 16; ++r0) {
        if (r0 & M) continue;
        if (S1 != 0 && (r0 & S1) != H1) continue;
        const int r1 = r0 + M;
        F2 a0 = amp[r0], a1 = amp[r1];
        F2 n0 = pk_cmul(u00, a0); pk_cfma(n0, u01, a1);
        F2 n1 = pk_cmul(u10, a0); pk_cfma(n1, u11, a1);
        amp[r0] = n0; amp[r1] = n1;
    }
}
template<int M, int S1, int H1>
__device__ __forceinline__ void g1qF(F2* amp, F8 u) {
    g1q<M, S1, H1>(amp, F2{u[0],u[1]}, F2{u[2],u[3]}, F2{u[4],u[5]}, F2{u[6],u[7]});
}

// REAL-input 1q gate (amp .y == 0): 4 pk/pair instead of 8.
template<int M>
__device__ __forceinline__ void g1qR(F2* amp, F8 u) {
    F2 u00{u[0],u[1]}, u01{u[2],u[3]}, u10{u[4],u[5]}, u11{u[6],u[7]};
#pragma unroll
    for (int r0 = 0; r0 < 16; ++r0) {
        if (r0 & M) continue;
        const int r1 = r0 + M;
        F2 a0 = amp[r0], a1 = amp[r1];   // .y = 0 (loaded real)
        F2 n0 = pk_smul(u00, a0); pk_sfma(n0, u01, a1);
        F2 n1 = pk_smul(u10, a0); pk_sfma(n1, u11, a1);
        amp[r0] = n0; amp[r1] = n1;
    }
}

// Fused gate: matrix selected per pair by compile-time control bit MSEL.
template<int MSEL, int M, int S1, int H1>
__device__ __forceinline__ void fg1q(F2* amp, F2 a00, F2 a01, F2 a10, F2 a11,
                                     F2 b00, F2 b01, F2 b10, F2 b11) {
#pragma unroll
    for (int r0 = 0; r0 < 16; ++r0) {
        if (r0 & M) continue;
        if (S1 != 0 && (r0 & S1) != H1) continue;
        const int r1 = r0 + M;
        const bool sel = (r0 & MSEL) != 0;           // compile-time
        F2 u00 = sel ? b00 : a00, u01 = sel ? b01 : a01;
        F2 u10 = sel ? b10 : a10, u11 = sel ? b11 : a11;
        F2 a0 = amp[r0], a1 = amp[r1];
        F2 n0 = pk_cmul(u00, a0); pk_cfma(n0, u01, a1);
        F2 n1 = pk_cmul(u10, a0); pk_cfma(n1, u11, a1);
        amp[r0] = n0; amp[r1] = n1;
    }
}
template<int MSEL, int M, int S1, int H1>
__device__ __forceinline__ void fg1qF(F2* amp, F8 a, F8 b) {
    fg1q<MSEL, M, S1, H1>(amp,
        F2{a[0],a[1]}, F2{a[2],a[3]}, F2{a[4],a[5]}, F2{a[6],a[7]},
        F2{b[0],b[1]}, F2{b[2],b[3]}, F2{b[4],b[5]}, F2{b[6],b[7]});
}

template<int MC, int MT>
__device__ __forceinline__ void crx(F2* amp, F2 cs) {   // cs in SGPRs
#pragma unroll
    for (int r0 = 0; r0 < 16; ++r0) {
        if (!(r0 & MC) || (r0 & MT)) continue;
        const int r1 = r0 + MT;
        F2 a0 = amp[r0], a1 = amp[r1];
        F2 n0 = pk_mul_bl(a0, cs); pk_swapneg(n0, a1, cs);
        F2 n1 = pk_mul_bl(a1, cs); pk_swapneg(n1, a0, cs);
        amp[r0] = n0; amp[r1] = n1;
    }
}

// expv: zp-trick (no zm; Z = 2*Sum|a0|^2 - 1 applied in final combine);
// raw partials stored (2x folded into final). DPP wave-sum (no LDS pipe).
template<int M>
__device__ __forceinline__ void expv(const F2* amp, int q, int lane,
                                     float& fx, float& fy, float& fz) {
    F2 zp = {0.f, 0.f}, xp = {0.f, 0.f}, ip = {0.f, 0.f};
#pragma unroll
    for (int r0 = 0; r0 < 16; ++r0) {
        if (r0 & M) continue;
        const int r1 = r0 + M;
        F2 a0 = amp[r0], a1 = amp[r1];
        pk_fma(zp, a0, a0);
        pk_fma(xp, a0, a1);
        pk_imacc(ip, a0, a1);
    }
    float tzz = wsum(zp.x + zp.y);   // partial Sum |a0|^2
    float txr = wsum(xp.x + xp.y);   // partial Re(conj(a0) a1)
    float txi = wsum(ip.x + ip.y);   // partial Im(conj(a0) a1)
    if (lane == q) { fx = txr; fy = txi; fz = tzz; }
}

// enumerate j-th pair base r0 with (r0 & M)==0 and (r0 & SB)==hb*SB (4-bit regs)
template<int M, int SB>
__device__ __forceinline__ int r0_of(int j, int hb) {
    int r = hb ? SB : 0, b = 1;
#pragma unroll
    for (int p = 0; p < 4; ++p) {
        const int mm = 1 << p;
        if (mm == M || mm == SB) continue;
        if (j & b) r |= mm;
        b <<= 1;
    }
    return r;
}

// Store one half (8 regs with (r & SB) == HB).
#define ST_T(TP, RP, SB, HB) \
  { _Pragma("unroll") for (int r = 0; r < 16; ++r) { \
      if ((r & (SB)) != (HB)) continue; \
      psi[(TP) ^ RP(r)] = amp[r]; } }
// Load one half in pair order of the next gate (mask M).
#define LD_T(TP, RP, M, SB, HB) \
  { _Pragma("unroll") for (int k = 0; k < 8; ++k) { \
      const int j = k >> 1; \
      const int r0 = r0_of<M, SB>(j, (HB) != 0); \
      const int r = (k & 1) ? (r0 + (M)) : r0; \
      amp[r] = psi[(TP) ^ RP(r)]; } }

#define U0P(q, M)    g1qF<M, 0, 0>(amp, sld8(cf + (q)*8))
#define FU0(q, MS, M) do { F8 ua_, ub_; sld16(cf + (q)*8, cf + 96 + (q)*8, ua_, ub_); \
                           fg1qF<MS, M, 0, 0>(amp, ua_, ub_); } while(0)
#define U1P(q, M)    g1qF<M, 0, 0>(amp, sld8(cf + 192 + (q)*8))
#define FU1_0()      do { F8 ua_, ub_; sld16(cf + 192, cf + 288, ua_, ub_); \
                          fg1qF<4, 8, 0, 0>(amp, ua_, ub_); } while(0)
#define CR1(c, MC, MT) crx<MC, MT>(amp, sld2(cf + 296 + (c)*2))
#define EXPV(q, M)   expv<M>(amp, q, l, fx, fy, fz)

__global__ __launch_bounds__(256, 1)
void qsim_kernel(const float* __restrict__ sv,      // [B, 4096]
                 const float* __restrict__ cf,      // [320] precomputed coefficients
                 const float* __restrict__ W,       // [10, 36]
                 const float* __restrict__ bvec,    // [10]
                 float* __restrict__ out)           // [B, 10]
{
    __shared__ F2 psi[2048];         // 16 KB split-transpose buffer
    const int t = threadIdx.x;
    const int b = blockIdx.x;
    const int l = t & 63, w = t >> 6;

    F2 amp[16];
    const float* svb = sv + (size_t)b * DIM;
    // layout A: idx = r<<8 | l<<2 | w; pair order for first gate (M=8)
#pragma unroll
    for (int k = 0; k < 16; ++k) {
        const int r = (k & 1) ? ((k >> 1) + 8) : (k >> 1);
        amp[r] = make_float2(svb[(r << 8) | (l << 2) | w], 0.f);
    }

    float fx = 0.f, fy = 0.f, fz = 0.f;

    // ---- A {q0:8 q1:4 q2:2 q3:1}: U0(0) real-input; [U0;CR0] q=1..3 ----
    g1qR<8>(amp, sld8(cf + 0));
    FU0(1, 8, 4); FU0(2, 4, 2); FU0(3, 2, 1);

    // ---- T1 A->B (internal, del a8, SB=1): halfgate FU0(4,1,4) ----
    {
        F8 ua, ub; sld16(cf + 4*8, cf + 96 + 4*8, ua, ub);
        const int tpA = tpA1f(l, w), tpB = tpB1f(l, w);
        ST_T(tpA, rpA1, 1, 0);
        LD_T(tpB, rpB1, 4, 1, 0);
        ST_T(tpA, rpA1, 1, 1);
        fg1qF<1, 4, 1, 0>(amp, ua, ub);
        LD_T(tpB, rpB1, 4, 1, 1);
        fg1qF<1, 4, 1, 1>(amp, ua, ub);
    }
    // ---- B {q3:1 q4:4 q5:8 q6:2} ----
    FU0(5, 4, 8); FU0(6, 8, 2);

    // ---- T2 B->C (internal, del a5, SB=2): halfgate FU0(7,2,4) ----
    {
        F8 ua, ub; sld16(cf + 7*8, cf + 96 + 7*8, ua, ub);
        const int tpB = tpB1f(l, w), tpC = tpC2f(l, w);
        ST_T(tpB, rpB2, 2, 0);
        LD_T(tpC, rpC2, 4, 2, 0);
        ST_T(tpB, rpB2, 2, 2);
        fg1qF<2, 4, 2, 0>(amp, ua, ub);
        LD_T(tpC, rpC2, 4, 2, 2);
        fg1qF<2, 4, 2, 2>(amp, ua, ub);
    }
    // ---- C {q6:2 q7:4 q8:8 q9:1} ----
    FU0(8, 4, 8); FU0(9, 8, 1);

    // ---- T3 C->D (CROSS, del a2, SB=1): halfgate FU0(10,1,2) ----
    {
        F8 ua, ub; sld16(cf + 10*8, cf + 96 + 10*8, ua, ub);
        __syncthreads();             // T2 slots not wave-disjoint vs T3 stores
        const int tpC = tpC3f(l, w), tpD = tpD3f(l, w);
        ST_T(tpC, rpC3, 1, 0);
        __syncthreads();
        LD_T(tpD, rpD3, 2, 1, 0);
        __syncthreads();
        ST_T(tpC, rpC3, 1, 1);
        fg1qF<1, 2, 1, 0>(amp, ua, ub);
        __syncthreads();
        LD_T(tpD, rpD3, 2, 1, 1);
        fg1qF<1, 2, 1, 1>(amp, ua, ub);
    }
    // ---- D {q9:1 q10:2 q11:4 q0:8}: [CR0(11,0);U1(0)]; U1(9..11);
    //      L1 ring (11,0),(10,11),(9,10); expv 10,11 ----
    FU0(11, 2, 4);
    FU1_0();
    U1P(9, 1); U1P(10, 2); U1P(11, 4);
    CR1(11, 4, 8); CR1(10, 2, 4); CR1(9, 1, 2);
    EXPV(10, 2); EXPV(11, 4);

    // ---- T4 D->C' (internal, del a2, SB=1): halfgate U1P(7,4) ----
    // no barrier: T3-LD and T4-ST slots both carry a7a6=wave at f10,f9
    {
        F8 u7 = sld8(cf + 192 + 7*8);
        const int tpD = tpD3f(l, w), tpC = tpC4f(l, w);
        ST_T(tpD, rpD3, 1, 0);
        LD_T(tpC, rpC3, 4, 1, 0);
        ST_T(tpD, rpD3, 1, 1);
        g1qF<4, 1, 0>(amp, u7);
        LD_T(tpC, rpC3, 4, 1, 1);
        g1qF<4, 1, 1>(amp, u7);
    }
    // ---- C' {q6:2 q7:4 q8:8 q9:1}: U1(6,8); ring (8,9),(7,8),(6,7); expv 7,8,9 ----
    U1P(6, 2); U1P(8, 8);
    CR1(8, 8, 1); CR1(7, 4, 8); CR1(6, 2, 4);
    EXPV(9, 1); EXPV(8, 8); EXPV(7, 4);

    // ---- T5 C'->B' (CROSS, del a5, SB=2): halfgate U1P(3,1) ----
    // no leading barrier: T4-LD and T5-ST slots both carry a7a6=wave at f10,f9
    {
        F8 u3 = sld8(cf + 192 + 3*8);
        const int tpC = tpC5f(l, w), tpB = tpB5f(l, w);
        ST_T(tpC, rpC5, 2, 0);
        __syncthreads();
        LD_T(tpB, rpB5, 1, 2, 0);
        __syncthreads();
        ST_T(tpC, rpC5, 2, 2);
        g1qF<1, 2, 0>(amp, u3);
        __syncthreads();
        LD_T(tpB, rpB5, 1, 2, 2);
        g1qF<1, 2, 2>(amp, u3);
        __syncthreads();             // protect cross-wave reads from T6 stores
    }
    // ---- B' {q3:1 q4:4 q5:8 q6:2}: U1(4,5); ring (5,6),(4,5),(3,4); expv 4,5,6 ----
    U1P(4, 4); U1P(5, 8);
    CR1(5, 8, 2); CR1(4, 4, 8); CR1(3, 1, 4);
    EXPV(6, 2); EXPV(5, 8); EXPV(4, 4);

    // ---- T6 B'->A' (internal, del a8, SB=1): halfgate U1P(1,4) ----
    {
        F8 u1 = sld8(cf + 192 + 1*8);
        const int tpB = tpB1f(l, w), tpA = tpA1f(l, w);
        ST_T(tpB, rpB1, 1, 0);
        LD_T(tpA, rpA1, 4, 1, 0);
        ST_T(tpB, rpB1, 1, 1);
        g1qF<4, 1, 0>(amp, u1);
        LD_T(tpA, rpA1, 4, 1, 1);
        g1qF<4, 1, 1>(amp, u1);
    }
    // ---- A' {q0:8 q1:4 q2:2 q3:1}: U1(2); ring (2,3),(1,2),(0,1); expv 0..3 ----
    U1P(2, 2);
    CR1(2, 2, 1); CR1(1, 4, 2); CR1(0, 8, 4);
    EXPV(3, 1); EXPV(2, 2); EXPV(1, 4); EXPV(0, 8);

    // ---- combine 4 waves' partial features ----
    __syncthreads();                 // psi dead only after all waves' T6 loads
    float* fbuf = (float*)psi;       // [4][36]
    if (l < 12) {
        fbuf[w * 36 + l]      = fx;
        fbuf[w * 36 + 12 + l] = fy;
        fbuf[w * 36 + 24 + l] = fz;
    }
    __syncthreads();
    if (t < 10) {
        float a = bvec[t];
        // features: X,Y = 2*s ; Z = 2*s - 1  (zp-trick fix-up, f>=24 are Z)
#pragma unroll
        for (int f = 0; f < 36; ++f) {
            const float wv = W[t * 36 + f];
            const float s = fbuf[f] + fbuf[36 + f] + fbuf[72 + f] + fbuf[108 + f];
            a += wv * (2.f * s);
            if (f >= 24) a -= wv;
        }
        out[(size_t)b * 10 + t] = a;
    }
}

extern "C" void kernel_launch(void* const* d_in, const int* in_sizes, int n_in,
                              void* d_out, int out_size, void* d_ws, size_t ws_size,
                              hipStream_t stream) {
    const float* sv     = (const float*)d_in[0];
    const float* angles = (const float*)d_in[1];
    const float* W      = (const float*)d_in[2];
    const float* bvec   = (const float*)d_in[3];
    float* out  = (float*)d_out;
    float* coef = (float*)d_ws;      // 320 floats of scratch
    int batch = in_sizes[0] / DIM;   // 2048
    prep_kernel<<<1, 64, 0, stream>>>(angles, coef);
    qsim_kernel<<<batch, 256, 0, stream>>>(sv, coef, W, bvec, out);
}

// Round 11
// 122.181 us; speedup vs baseline: 1.2093x; 1.0249x over previous
//
#include <hip/hip_runtime.h>

#define DIM 4096
using F2 = float2;
using F8 = __attribute__((ext_vector_type(8))) float;
using F2V = __attribute__((ext_vector_type(2))) float;

// R24 = R23 (champion, qsim 55.1 us, VGPR 60) + EXPV-drain placement
// (R13-proven mechanism): EXPVs moved from before T4/T5/T6 to right after
// each transpose's ST-h0 — they read amp regs only (intact until LD-h0
// overwrites), so they fill the store-drain / cross-wave barrier-arrival
// window instead of idling. Everything else byte-identical to R23.
// Rejected this round by analysis: LD-h0/ST-h1 barrier merge (ILLEGAL —
// halves reuse the same 16KB slots; split bit is deleted from compressed
// space, so that barrier is a real WAR guard); 32KB cross-transposes
// (saves 4 barriers, costs 8->5 blocks/CU; busy-vs-supply curve predicts
// net loss); CR1(11) fusion into FU1_0 (order-illegal, U1(11) intervenes);
// b128 transposes (needs a phys bit that is a reg bit of BOTH layouts =
// the deleted split bit -> impossible).
//
// Address bits: qubit q <-> a[11-q]. Layouts (reg bit value in parens):
//  A : regs a11(8) a10(4) a9(2) a8(1); lanes a7..a2=l5..l0; wave a1a0
//      masks: q0:8 q1:4 q2:2 q3:1
//  B : regs a8(1) a7(4) a6(8) a5(2); lanes a11,a10,a9,a4,a3,a2=l5..l0; wave a1a0
//      masks: q3:1 q4:4 q5:8 q6:2
//  C : regs a5(2) a4(4) a3(8) a2(1); lanes a11..a6=l5..l0; wave a1a0
//      masks: q6:2 q7:4 q8:8 q9:1
//  D : regs a2(1) a1(2) a0(4) a11(8); lanes a10,a9,a8,a5,a4,a3=l5..l0; wave a7a6
//      masks: q9:1 q10:2 q11:4 q0:8
//  C': regs as C; lanes a11,a10,a9,a8,a1,a0=l5..l0; wave a7a6
//  B': = B.   A': = A.
// Transitions: T1 A->B del a8 SB=1 internal; T2 B->C del a5 SB=2 internal;
//  T3 C->D del a2 SB=1 CROSS; T4 D->C' del a2 SB=1 internal;
//  T5 C'->B' del a5 SB=2 CROSS; T6 B'->A' del a8 SB=1 internal.
// __launch_bounds__(256,1): min_waves>=6 coerces allocator into amp[]
// scratch spill (R16-R18 forensics); (.,1) never spilled.

// ---- scalar coefficient loads (SMEM) ----
__device__ __forceinline__ F8 sld8(const float* p) {
    F8 r;
    asm volatile("s_load_dwordx8 %0, %1, 0x0\n\ts_waitcnt lgkmcnt(0)"
                 : "=s"(r) : "s"(p));
    return r;
}
__device__ __forceinline__ void sld16(const float* pa, const float* pb, F8& a, F8& b) {
    asm volatile("s_load_dwordx8 %0, %2, 0x0\n\t"
                 "s_load_dwordx8 %1, %3, 0x0\n\t"
                 "s_waitcnt lgkmcnt(0)"
                 : "=&s"(a), "=&s"(b) : "s"(pa), "s"(pb));
}
__device__ __forceinline__ F2 sld2(const float* p) {
    F2V r;
    asm volatile("s_load_dwordx2 %0, %1, 0x0\n\ts_waitcnt lgkmcnt(0)"
                 : "=s"(r) : "s"(p));
    return F2{r[0], r[1]};
}

// ---- packed fp32 complex primitives (VOP3P), coefficient operand in SGPRs ----
__device__ __forceinline__ F2 pk_mul_bl(F2 a, F2 u) {   // (a.x*u.x, a.y*u.x)
    F2 d;
    asm("v_pk_mul_f32 %0, %1, %2 op_sel:[0,0] op_sel_hi:[1,0]"
        : "=v"(d) : "v"(a), "s"(u));
    return d;
}
__device__ __forceinline__ void pk_cross(F2& d, F2 a, F2 u) {  // d += (-a.y*u.y, a.x*u.y)
    asm("v_pk_fma_f32 %0, %1, %2, %0 op_sel:[1,1,0] op_sel_hi:[0,1,1] neg_lo:[1,0,0]"
        : "+v"(d) : "v"(a), "s"(u));
}
__device__ __forceinline__ void pk_fma_bl(F2& d, F2 a, F2 u) { // d += (a.x*u.x, a.y*u.x)
    asm("v_pk_fma_f32 %0, %1, %2, %0 op_sel:[0,0,0] op_sel_hi:[1,0,1]"
        : "+v"(d) : "v"(a), "s"(u));
}
__device__ __forceinline__ void pk_swapneg(F2& d, F2 a, F2 cs) { // d += (a.y*cs.y, -a.x*cs.y)
    asm("v_pk_fma_f32 %0, %1, %2, %0 op_sel:[1,1,0] op_sel_hi:[0,1,1] neg_hi:[1,0,0]"
        : "+v"(d) : "v"(a), "s"(cs));
}
// swapped-constraint twins for the REAL-input first gate (proven R23)
__device__ __forceinline__ F2 pk_smul(F2 u, F2 s) {    // (u.x*s.x, u.y*s.x)
    F2 d;
    asm("v_pk_mul_f32 %0, %1, %2 op_sel:[0,0] op_sel_hi:[1,0]"
        : "=v"(d) : "s"(u), "v"(s));
    return d;
}
__device__ __forceinline__ void pk_sfma(F2& d, F2 u, F2 s) { // d += (u.x*s.x, u.y*s.x)
    asm("v_pk_fma_f32 %0, %1, %2, %0 op_sel:[0,0,0] op_sel_hi:[1,0,1]"
        : "+v"(d) : "s"(u), "v"(s));
}
// all-VGPR variants (expv: both operands are lane data)
__device__ __forceinline__ void pk_fma(F2& d, F2 a, F2 b) {    // d += a*b
    asm("v_pk_fma_f32 %0, %1, %2, %0" : "+v"(d) : "v"(a), "v"(b));
}
__device__ __forceinline__ void pk_imacc(F2& d, F2 a0, F2 a1) { // d += (a0.x*a1.y, -a0.y*a1.x)
    asm("v_pk_fma_f32 %0, %1, %2, %0 op_sel:[0,1,0] op_sel_hi:[1,0,1] neg_hi:[1,0,0]"
        : "+v"(d) : "v"(a0), "v"(a1));
}
__device__ __forceinline__ F2 pk_cmul(F2 u, F2 a) {
    F2 d = pk_mul_bl(a, u);
    pk_cross(d, a, u);
    return d;
}
__device__ __forceinline__ void pk_cfma(F2& d, F2 u, F2 a) {
    pk_fma_bl(d, a, u);
    pk_cross(d, a, u);
}

// ---- VALU-only wave sum via DPP (proven R22). Total lands in lane 63. ----
__device__ __forceinline__ float wsum(float x) {
#define DPPADD(ctrl) \
    x += __builtin_bit_cast(float, __builtin_amdgcn_update_dpp( \
             0, __builtin_bit_cast(int, x), (ctrl), 0xf, 0xf, true))
    DPPADD(0x111);   // row_shr:1
    DPPADD(0x112);   // row_shr:2
    DPPADD(0x114);   // row_shr:4
    DPPADD(0x118);   // row_shr:8  -> lane r*16+15 = row sum
    DPPADD(0x142);   // row_bcast15 -> lane31 = r0+r1, lane63 = r2+r3
    DPPADD(0x143);   // row_bcast31 -> lane63 = total
#undef DPPADD
    return __builtin_bit_cast(float, __builtin_amdgcn_readlane(
               __builtin_bit_cast(int, x), 63));
}

__device__ __forceinline__ void build_u(float tx, float ty, float tz, float* u) {
    float sx = sinf(0.5f*tx), cx = cosf(0.5f*tx);
    float sy = sinf(0.5f*ty), cy = cosf(0.5f*ty);
    float sz = sinf(0.5f*tz), cz = cosf(0.5f*tz);
    float A00r = cy*cx, A00i =  sy*sx;     // A = Ry*Rx
    float A01r = -sy*cx, A01i = -cy*sx;
    float A10r =  sy*cx, A10i = -cy*sx;
    float A11r =  cy*cx, A11i = -sy*sx;
    // U = Rz*A: row0 *= (cz - i sz), row1 *= (cz + i sz)   [verified r1/3/5..23]
    u[0] = cz*A00r + sz*A00i;  u[1] = cz*A00i - sz*A00r;
    u[2] = cz*A01r + sz*A01i;  u[3] = cz*A01i - sz*A01r;
    u[4] = cz*A10r - sz*A10i;  u[5] = cz*A10i + sz*A10r;
    u[6] = cz*A11r - sz*A11i;  u[7] = cz*A11i + sz*A11r;
}

// coef layout (floats): [0..95] U0 plain (q*8); [96..191] RX(ang[36+q-1])*U0[q] (q=1..11);
// [192..287] U1 plain; [288..295] U1[0]*RX(ang[47]); [296..319] L1 CRX (cos,sin)[c=0..11]
__global__ void prep_kernel(const float* __restrict__ ang, float* __restrict__ coef) {
    int t = threadIdx.x;
    if (t < 12) {
        float u[8]; build_u(ang[t], ang[12+t], ang[24+t], u);
#pragma unroll
        for (int j = 0; j < 8; ++j) coef[t*8 + j] = u[j];
    } else if (t < 24) {
        int q = t - 12;
        float u[8]; build_u(ang[48+q], ang[60+q], ang[72+q], u);
#pragma unroll
        for (int j = 0; j < 8; ++j) coef[192 + q*8 + j] = u[j];
    } else if (t < 36) {
        int c = t - 24;
        float th = 0.5f * ang[95 - c];     // L1 ring gate (c,c+1) = tape slot 84+(11-c)
        coef[296 + c*2]     = cosf(th);
        coef[296 + c*2 + 1] = sinf(th);
    } else if (t < 47) {
        int q = t - 35;                    // 1..11: M = RX(ang[36+q-1]) * U0[q]
        float u[8]; build_u(ang[q], ang[12+q], ang[24+q], u);
        float c = cosf(0.5f*ang[36+q-1]), s = sinf(0.5f*ang[36+q-1]);
        float m[8];
        m[0] = c*u[0] + s*u[5];  m[1] = c*u[1] - s*u[4];   // M00 = c u00 - i s u10
        m[2] = c*u[2] + s*u[7];  m[3] = c*u[3] - s*u[6];   // M01 = c u01 - i s u11
        m[4] = s*u[1] + c*u[4];  m[5] = -s*u[0] + c*u[5];  // M10 = -i s u00 + c u10
        m[6] = s*u[3] + c*u[6];  m[7] = -s*u[2] + c*u[7];  // M11 = -i s u01 + c u11
#pragma unroll
        for (int j = 0; j < 8; ++j) coef[96 + q*8 + j] = m[j];
    } else if (t == 47) {                  // M = U1[0] * RX(ang[47])  [CR0(11,0) then U1(0)]
        float u[8]; build_u(ang[48], ang[60], ang[72], u);
        float c = cosf(0.5f*ang[47]), s = sinf(0.5f*ang[47]);
        float m[8];
        m[0] = c*u[0] + s*u[3];  m[1] = c*u[1] - s*u[2];   // M00 = c u00 - i s u01
        m[2] = s*u[1] + c*u[2];  m[3] = -s*u[0] + c*u[3];  // M01 = -i s u00 + c u01
        m[4] = c*u[4] + s*u[7];  m[5] = c*u[5] - s*u[6];   // M10 = c u10 - i s u11
        m[6] = s*u[5] + c*u[6];  m[7] = -s*u[4] + c*u[7];  // M11 = -i s u10 + c u11
#pragma unroll
        for (int j = 0; j < 8; ++j) coef[288 + j] = m[j];
    }
}

// ---- register-part (compile-time per unrolled r) of each packing ----
__device__ __forceinline__ int rpA1(int r) {   // T1/T6, A side (a8 deleted = r&1)
    int a11=(r>>3)&1, a10=(r>>2)&1, a9=(r>>1)&1;
    return (a11<<8)|(a10<<7)|(a9<<6)|(a11<<3)|(a10<<2)|(a9<<1)|(a9<<0);
}
__device__ __forceinline__ int rpB1(int r) {   // T1/T6, B side
    int a5=(r>>1)&1, a7=(r>>2)&1, a6=(r>>3)&1;
    return (a7<<5)|(a6<<4)|(a7<<3)|(a6<<2)|(a5<<0);
}
__device__ __forceinline__ int rpB2(int r) {   // T2, B side (a5 deleted = r&2)
    int a8=r&1, a7=(r>>2)&1, a6=(r>>3)&1;
    return (a8<<5)|(a7<<4)|(a6<<3)|(a7<<2)|(a8<<1)|(a6<<0);
}
__device__ __forceinline__ int rpC2(int r) {   // T2, C side
    int a2=r&1, a4=(r>>2)&1, a3=(r>>3)&1;
    return (a3<<3)|(a2<<2)|(a4<<1);
}
__device__ __forceinline__ int rpC3(int r) {   // T3/T4, C/C' side (a2 deleted = r&1)
    int a5=(r>>1)&1, a4=(r>>2)&1, a3=(r>>3)&1;
    return (a5<<4)|(a3<<3)|(a4<<2)|(a5<<0);
}
__device__ __forceinline__ int rpD3(int r) {   // T3/T4, D side
    int a1=(r>>1)&1, a0=(r>>2)&1, a11=(r>>3)&1;
    return (a11<<8)|(a11<<3)|(a1<<1)|((a0^a11)<<0);
}
__device__ __forceinline__ int rpC5(int r) {   // T5, C' side (a5 deleted = r&2)
    int a2=r&1, a4=(r>>2)&1, a3=(r>>3)&1;
    return (a4<<4)|(a3<<3)|(a2<<2)|(a4<<0);
}
__device__ __forceinline__ int rpB5(int r) {   // T5, B' side
    int a8=r&1, a7=(r>>2)&1, a6=(r>>3)&1;
    return (a7<<10)|(a6<<9)|(a8<<5)|(a8<<3);
}

// ---- tile pointers (lane/wave part of each packing); scoped per transpose ----
#define LBITS \
    const int l0=l&1, l1=(l>>1)&1, l2=(l>>2)&1, l3=(l>>3)&1, l4=(l>>4)&1, \
              l5=(l>>5)&1, w0=w&1, w1=(w>>1)&1; \
    (void)l0;(void)l1;(void)l2;(void)l3;(void)l4;(void)l5;(void)w0;(void)w1;

__device__ __forceinline__ int tpA1f(int l, int w) { LBITS
    return (w1<<10)|(w0<<9)|(l5<<5)|(l4<<4)|((l1^l5)<<3)|((l0^l4)<<2)|(l2<<1)|(l3<<0); }
__device__ __forceinline__ int tpB1f(int l, int w) { LBITS
    return (w1<<10)|(w0<<9)|(l5<<8)|(l4<<7)|(l3<<6)|((l1^l5)<<3)|((l0^l4)<<2)|((l2^l3)<<1)|(l3<<0); }
__device__ __forceinline__ int tpC2f(int l, int w) { LBITS
    return (w1<<10)|(w0<<9)|(l5<<8)|(l4<<7)|(l3<<6)|(l2<<5)|(l1<<4)|((l5^l0)<<3)|((l4^l1)<<2)|((l3^l2)<<1)|((l0^l3)<<0); }
__device__ __forceinline__ int tpC3f(int l, int w) { LBITS
    return (l1<<10)|(l0<<9)|(l5<<8)|(l4<<7)|(l3<<6)|(l2<<5)|((l5^l4)<<3)|(l3<<2)|((w1^l2)<<1)|((w0^l5)<<0); }
__device__ __forceinline__ int tpD3f(int l, int w) { LBITS
    return (w1<<10)|(w0<<9)|(l5<<7)|(l4<<6)|(l3<<5)|(l2<<4)|((l0^l5)<<3)|((l1^l4)<<2)|(l3<<1)|(l2<<0); }
__device__ __forceinline__ int tpC4f(int l, int w) { LBITS
    return (w1<<10)|(w0<<9)|(l5<<8)|(l4<<7)|(l3<<6)|(l2<<5)|((l5^l4)<<3)|(l3<<2)|((l1^l2)<<1)|((l0^l5)<<0); }
__device__ __forceinline__ int tpC5f(int l, int w) { LBITS
    return (w1<<10)|(w0<<9)|(l5<<8)|(l4<<7)|(l3<<6)|(l2<<5)|((l5^l2)<<3)|(l4<<2)|((l1^l3)<<1)|(l0<<0); }
__device__ __forceinline__ int tpB5f(int l, int w) { LBITS
    return (l5<<8)|(l4<<7)|(l3<<6)|(l2<<4)|((l1^l5)<<3)|((l0^l4)<<2)|((w1^l3)<<1)|((w0^l2)<<0); }

// Plain 1q gate over subset {r0: (r0&M)==0, (S1==0 || (r0&S1)==H1)};
// coefficients in SGPRs.
template<int M, int S1, int H1>
__device__ __forceinline__ void g1q(F2* amp, F2 u00, F2 u01, F2 u10, F2 u11) {
#pragma unroll
    for (int r0 = 0; r0 < 16; ++r0) {
        if (r0 & M) continue;
        if (S1 != 0 && (r0 & S1) != H1) continue;
        const int r1 = r0 + M;
        F2 a0 = amp[r0], a1 = amp[r1];
        F2 n0 = pk_cmul(u00, a0); pk_cfma(n0, u01, a1);
        F2 n1 = pk_cmul(u10, a0); pk_cfma(n1, u11, a1);
        amp[r0] = n0; amp[r1] = n1;
    }
}
template<int M, int S1, int H1>
__device__ __forceinline__ void g1qF(F2* amp, F8 u) {
    g1q<M, S1, H1>(amp, F2{u[0],u[1]}, F2{u[2],u[3]}, F2{u[4],u[5]}, F2{u[6],u[7]});
}

// REAL-input 1q gate (amp .y == 0): 4 pk/pair instead of 8.
template<int M>
__device__ __forceinline__ void g1qR(F2* amp, F8 u) {
    F2 u00{u[0],u[1]}, u01{u[2],u[3]}, u10{u[4],u[5]}, u11{u[6],u[7]};
#pragma unroll
    for (int r0 = 0; r0 < 16; ++r0) {
        if (r0 & M) continue;
        const int r1 = r0 + M;
        F2 a0 = amp[r0], a1 = amp[r1];   // .y = 0 (loaded real)
        F2 n0 = pk_smul(u00, a0); pk_sfma(n0, u01, a1);
        F2 n1 = pk_smul(u10, a0); pk_sfma(n1, u11, a1);
        amp[r0] = n0; amp[r1] = n1;
    }
}

// Fused gate: matrix selected per pair by compile-time control bit MSEL.
template<int MSEL, int M, int S1, int H1>
__device__ __forceinline__ void fg1q(F2* amp, F2 a00, F2 a01, F2 a10, F2 a11,
                                     F2 b00, F2 b01, F2 b10, F2 b11) {
#pragma unroll
    for (int r0 = 0; r0 < 16; ++r0) {
        if (r0 & M) continue;
        if (S1 != 0 && (r0 & S1) != H1) continue;
        const int r1 = r0 + M;
        const bool sel = (r0 & MSEL) != 0;           // compile-time
        F2 u00 = sel ? b00 : a00, u01 = sel ? b01 : a01;
        F2 u10 = sel ? b10 : a10, u11 = sel ? b11 : a11;
        F2 a0 = amp[r0], a1 = amp[r1];
        F2 n0 = pk_cmul(u00, a0); pk_cfma(n0, u01, a1);
        F2 n1 = pk_cmul(u10, a0); pk_cfma(n1, u11, a1);
        amp[r0] = n0; amp[r1] = n1;
    }
}
template<int MSEL, int M, int S1, int H1>
__device__ __forceinline__ void fg1qF(F2* amp, F8 a, F8 b) {
    fg1q<MSEL, M, S1, H1>(amp,
        F2{a[0],a[1]}, F2{a[2],a[3]}, F2{a[4],a[5]}, F2{a[6],a[7]},
        F2{b[0],b[1]}, F2{b[2],b[3]}, F2{b[4],b[5]}, F2{b[6],b[7]});
}

template<int MC, int MT>
__device__ __forceinline__ void crx(F2* amp, F2 cs) {   // cs in SGPRs
#pragma unroll
    for (int r0 = 0; r0 < 16; ++r0) {
        if (!(r0 & MC) || (r0 & MT)) continue;
        const int r1 = r0 + MT;
        F2 a0 = amp[r0], a1 = amp[r1];
        F2 n0 = pk_mul_bl(a0, cs); pk_swapneg(n0, a1, cs);
        F2 n1 = pk_mul_bl(a1, cs); pk_swapneg(n1, a0, cs);
        amp[r0] = n0; amp[r1] = n1;
    }
}

// expv: zp-trick (no zm; Z = 2*Sum|a0|^2 - 1 applied in final combine);
// raw partials stored. DPP wave-sum (no LDS pipe).
template<int M>
__device__ __forceinline__ void expv(const F2* amp, int q, int lane,
                                     float& fx, float& fy, float& fz) {
    F2 zp = {0.f, 0.f}, xp = {0.f, 0.f}, ip = {0.f, 0.f};
#pragma unroll
    for (int r0 = 0; r0 < 16; ++r0) {
        if (r0 & M) continue;
        const int r1 = r0 + M;
        F2 a0 = amp[r0], a1 = amp[r1];
        pk_fma(zp, a0, a0);
        pk_fma(xp, a0, a1);
        pk_imacc(ip, a0, a1);
    }
    float tzz = wsum(zp.x + zp.y);   // partial Sum |a0|^2
    float txr = wsum(xp.x + xp.y);   // partial Re(conj(a0) a1)
    float txi = wsum(ip.x + ip.y);   // partial Im(conj(a0) a1)
    if (lane == q) { fx = txr; fy = txi; fz = tzz; }
}

// enumerate j-th pair base r0 with (r0 & M)==0 and (r0 & SB)==hb*SB (4-bit regs)
template<int M, int SB>
__device__ __forceinline__ int r0_of(int j, int hb) {
    int r = hb ? SB : 0, b = 1;
#pragma unroll
    for (int p = 0; p < 4; ++p) {
        const int mm = 1 << p;
        if (mm == M || mm == SB) continue;
        if (j & b) r |= mm;
        b <<= 1;
    }
    return r;
}

// Store one half (8 regs with (r & SB) == HB).
#define ST_T(TP, RP, SB, HB) \
  { _Pragma("unroll") for (int r = 0; r < 16; ++r) { \
      if ((r & (SB)) != (HB)) continue; \
      psi[(TP) ^ RP(r)] = amp[r]; } }
// Load one half in pair order of the next gate (mask M).
#define LD_T(TP, RP, M, SB, HB) \
  { _Pragma("unroll") for (int k = 0; k < 8; ++k) { \
      const int j = k >> 1; \
      const int r0 = r0_of<M, SB>(j, (HB) != 0); \
      const int r = (k & 1) ? (r0 + (M)) : r0; \
      amp[r] = psi[(TP) ^ RP(r)]; } }

#define U0P(q, M)    g1qF<M, 0, 0>(amp, sld8(cf + (q)*8))
#define FU0(q, MS, M) do { F8 ua_, ub_; sld16(cf + (q)*8, cf + 96 + (q)*8, ua_, ub_); \
                           fg1qF<MS, M, 0, 0>(amp, ua_, ub_); } while(0)
#define U1P(q, M)    g1qF<M, 0, 0>(amp, sld8(cf + 192 + (q)*8))
#define FU1_0()      do { F8 ua_, ub_; sld16(cf + 192, cf + 288, ua_, ub_); \
                          fg1qF<4, 8, 0, 0>(amp, ua_, ub_); } while(0)
#define CR1(c, MC, MT) crx<MC, MT>(amp, sld2(cf + 296 + (c)*2))
#define EXPV(q, M)   expv<M>(amp, q, l, fx, fy, fz)

__global__ __launch_bounds__(256, 1)
void qsim_kernel(const float* __restrict__ sv,      // [B, 4096]
                 const float* __restrict__ cf,      // [320] precomputed coefficients
                 const float* __restrict__ W,       // [10, 36]
                 const float* __restrict__ bvec,    // [10]
                 float* __restrict__ out)           // [B, 10]
{
    __shared__ F2 psi[2048];         // 16 KB split-transpose buffer
    const int t = threadIdx.x;
    const int b = blockIdx.x;
    const int l = t & 63, w = t >> 6;

    F2 amp[16];
    const float* svb = sv + (size_t)b * DIM;
    // layout A: idx = r<<8 | l<<2 | w; pair order for first gate (M=8)
#pragma unroll
    for (int k = 0; k < 16; ++k) {
        const int r = (k & 1) ? ((k >> 1) + 8) : (k >> 1);
        amp[r] = make_float2(svb[(r << 8) | (l << 2) | w], 0.f);
    }

    float fx = 0.f, fy = 0.f, fz = 0.f;

    // ---- A {q0:8 q1:4 q2:2 q3:1}: U0(0) real-input; [U0;CR0] q=1..3 ----
    g1qR<8>(amp, sld8(cf + 0));
    FU0(1, 8, 4); FU0(2, 4, 2); FU0(3, 2, 1);

    // ---- T1 A->B (internal, del a8, SB=1): halfgate FU0(4,1,4) ----
    {
        F8 ua, ub; sld16(cf + 4*8, cf + 96 + 4*8, ua, ub);
        const int tpA = tpA1f(l, w), tpB = tpB1f(l, w);
        ST_T(tpA, rpA1, 1, 0);
        LD_T(tpB, rpB1, 4, 1, 0);
        ST_T(tpA, rpA1, 1, 1);
        fg1qF<1, 4, 1, 0>(amp, ua, ub);
        LD_T(tpB, rpB1, 4, 1, 1);
        fg1qF<1, 4, 1, 1>(amp, ua, ub);
    }
    // ---- B {q3:1 q4:4 q5:8 q6:2} ----
    FU0(5, 4, 8); FU0(6, 8, 2);

    // ---- T2 B->C (internal, del a5, SB=2): halfgate FU0(7,2,4) ----
    {
        F8 ua, ub; sld16(cf + 7*8, cf + 96 + 7*8, ua, ub);
        const int tpB = tpB1f(l, w), tpC = tpC2f(l, w);
        ST_T(tpB, rpB2, 2, 0);
        LD_T(tpC, rpC2, 4, 2, 0);
        ST_T(tpB, rpB2, 2, 2);
        fg1qF<2, 4, 2, 0>(amp, ua, ub);
        LD_T(tpC, rpC2, 4, 2, 2);
        fg1qF<2, 4, 2, 2>(amp, ua, ub);
    }
    // ---- C {q6:2 q7:4 q8:8 q9:1} ----
    FU0(8, 4, 8); FU0(9, 8, 1);

    // ---- T3 C->D (CROSS, del a2, SB=1): halfgate FU0(10,1,2) ----
    {
        F8 ua, ub; sld16(cf + 10*8, cf + 96 + 10*8, ua, ub);
        __syncthreads();             // T2 slots not wave-disjoint vs T3 stores
        const int tpC = tpC3f(l, w), tpD = tpD3f(l, w);
        ST_T(tpC, rpC3, 1, 0);
        __syncthreads();
        LD_T(tpD, rpD3, 2, 1, 0);
        __syncthreads();             // WAR: h1 stores reuse h0's slots
        ST_T(tpC, rpC3, 1, 1);
        fg1qF<1, 2, 1, 0>(amp, ua, ub);
        __syncthreads();
        LD_T(tpD, rpD3, 2, 1, 1);
        fg1qF<1, 2, 1, 1>(amp, ua, ub);
    }
    // ---- D {q9:1 q10:2 q11:4 q0:8}: [CR0(11,0);U1(0)]; U1(9..11);
    //      L1 ring (11,0),(10,11),(9,10) ----
    FU0(11, 2, 4);
    FU1_0();
    U1P(9, 1); U1P(10, 2); U1P(11, 4);
    CR1(11, 4, 8); CR1(10, 2, 4); CR1(9, 1, 2);

    // ---- T4 D->C' (internal, del a2, SB=1): halfgate U1P(7,4) ----
    // EXPV(10),(11) moved after ST h0: they read amp regs only (intact
    // until LD h0 overwrites) and fill the store drain [R13 mechanism].
    {
        F8 u7 = sld8(cf + 192 + 7*8);
        const int tpD = tpD3f(l, w), tpC = tpC4f(l, w);
        ST_T(tpD, rpD3, 1, 0);
        EXPV(10, 2); EXPV(11, 4);
        LD_T(tpC, rpC3, 4, 1, 0);
        ST_T(tpD, rpD3, 1, 1);
        g1qF<4, 1, 0>(amp, u7);
        LD_T(tpC, rpC3, 4, 1, 1);
        g1qF<4, 1, 1>(amp, u7);
    }
    // ---- C' {q6:2 q7:4 q8:8 q9:1}: U1(6,8); ring (8,9),(7,8),(6,7) ----
    U1P(6, 2); U1P(8, 8);
    CR1(8, 8, 1); CR1(7, 4, 8); CR1(6, 2, 4);

    // ---- T5 C'->B' (CROSS, del a5, SB=2): halfgate U1P(3,1) ----
    // EXPV(9),(8),(7) after ST h0, before the barrier: covers the
    // cross-wave store drain / barrier-arrival window.
    {
        F8 u3 = sld8(cf + 192 + 3*8);
        const int tpC = tpC5f(l, w), tpB = tpB5f(l, w);
        ST_T(tpC, rpC5, 2, 0);
        EXPV(9, 1); EXPV(8, 8); EXPV(7, 4);
        __syncthreads();
        LD_T(tpB, rpB5, 1, 2, 0);
        __syncthreads();             // WAR: h1 stores reuse h0's slots
        ST_T(tpC, rpC5, 2, 2);
        g1qF<1, 2, 0>(amp, u3);
        __syncthreads();
        LD_T(tpB, rpB5, 1, 2, 2);
        g1qF<1, 2, 2>(amp, u3);
        __syncthreads();             // protect cross-wave reads from T6 stores
    }
    // ---- B' {q3:1 q4:4 q5:8 q6:2}: U1(4,5); ring (5,6),(4,5),(3,4) ----
    U1P(4, 4); U1P(5, 8);
    CR1(5, 8, 2); CR1(4, 4, 8); CR1(3, 1, 4);

    // ---- T6 B'->A' (internal, del a8, SB=1): halfgate U1P(1,4) ----
    // EXPV(6),(5),(4) after ST h0 (drain fill).
    {
        F8 u1 = sld8(cf + 192 + 1*8);
        const int tpB = tpB1f(l, w), tpA = tpA1f(l, w);
        ST_T(tpB, rpB1, 1, 0);
        EXPV(6, 2); EXPV(5, 8); EXPV(4, 4);
        LD_T(tpA, rpA1, 4, 1, 0);
        ST_T(tpB, rpB1, 1, 1);
        g1qF<4, 1, 0>(amp, u1);
        LD_T(tpA, rpA1, 4, 1, 1);
        g1qF<4, 1, 1>(amp, u1);
    }
    // ---- A' {q0:8 q1:4 q2:2 q3:1}: U1(2); ring (2,3),(1,2),(0,1); expv 0..3 ----
    U1P(2, 2);
    CR1(2, 2, 1); CR1(1, 4, 2); CR1(0, 8, 4);
    EXPV(3, 1); EXPV(2, 2); EXPV(1, 4); EXPV(0, 8);

    // ---- combine 4 waves' partial features ----
    __syncthreads();                 // psi dead only after all waves' T6 loads
    float* fbuf = (float*)psi;       // [4][36]
    if (l < 12) {
        fbuf[w * 36 + l]      = fx;
        fbuf[w * 36 + 12 + l] = fy;
        fbuf[w * 36 + 24 + l] = fz;
    }
    __syncthreads();
    if (t < 10) {
        float a = bvec[t];
        // features: X,Y = 2*s ; Z = 2*s - 1  (zp-trick fix-up, f>=24 are Z)
#pragma unroll
        for (int f = 0; f < 36; ++f) {
            const float wv = W[t * 36 + f];
            const float s = fbuf[f] + fbuf[36 + f] + fbuf[72 + f] + fbuf[108 + f];
            a += wv * (2.f * s);
            if (f >= 24) a -= wv;
        }
        out[(size_t)b * 10 + t] = a;
    }
}

extern "C" void kernel_launch(void* const* d_in, const int* in_sizes, int n_in,
                              void* d_out, int out_size, void* d_ws, size_t ws_size,
                              hipStream_t stream) {
    const float* sv     = (const float*)d_in[0];
    const float* angles = (const float*)d_in[1];
    const float* W      = (const float*)d_in[2];
    const float* bvec   = (const float*)d_in[3];
    float* out  = (float*)d_out;
    float* coef = (float*)d_ws;      // 320 floats of scratch
    int batch = in_sizes[0] / DIM;   // 2048
    prep_kernel<<<1, 64, 0, stream>>>(angles, coef);
    qsim_kernel<<<batch, 256, 0, stream>>>(sv, coef, W, bvec, out);
}